// Round 16
// baseline (276.156 us; speedup 1.0000x reference)
//
#include <hip/hip_runtime.h>

// GAT (2-layer, PyG GATConv semantics) on MI355X — src-major aggregation,
// bf16-split MFMA for BOTH the feature GEMM and the edge-logit GEMM.
// N=20000 nodes, E=100000 edges (+N self-loops), D=64, H=16 heads, C=64 ch/head.
constexpr int TD  = 64;      // input feature dim
constexpr int TH  = 16;      // heads
constexpr int TC  = 64;      // channels per head
constexpr int THC = TH * TC; // 1024

typedef short bf16x8 __attribute__((ext_vector_type(8)));
typedef unsigned short u16x8 __attribute__((ext_vector_type(8)));
typedef float f32x4 __attribute__((ext_vector_type(4)));

static __device__ __forceinline__ unsigned short f2bf(float f) {  // RNE f32->bf16
  unsigned u = __float_as_uint(f);
  u += 0x7FFF + ((u >> 16) & 1);
  return (unsigned short)(u >> 16);
}
static __device__ __forceinline__ float bf2f(unsigned short h) {
  return __uint_as_float(((unsigned)h) << 16);
}

// ---------------- CSR/CSC build (once, shared by both layers) ----------------

__global__ void k_count2(const int* __restrict__ src, const int* __restrict__ dst,
                         int E, int N, int* __restrict__ degd, int* __restrict__ degs) {
  int e = blockIdx.x * blockDim.x + threadIdx.x;
  if (e >= E + N) return;
  int s, d;
  if (e < E) { s = src[e]; d = dst[e]; } else { s = d = e - E; }
  atomicAdd(&degd[d], 1);
  atomicAdd(&degs[s], 1);
}

// hierarchical exclusive scan, 1024 threads (R13->R14: 48us serial -> off top-5).
// block 0: dst-CSR, block 1: src-CSR.
__global__ __launch_bounds__(1024) void k_scan2(
    const int* __restrict__ degd, int N,
    int* __restrict__ row_start, int* __restrict__ cursor,
    const int* __restrict__ degs,
    int* __restrict__ srow, int* __restrict__ scursor) {
  const int* dg = blockIdx.x ? degs : degd;
  int* rs = blockIdx.x ? srow : row_start;
  int* cu = blockIdx.x ? scursor : cursor;
  __shared__ int wsum[16];
  int t = threadIdx.x;
  int chunk = (N + 1023) / 1024;
  int lo = min(t * chunk, N), hi = min(lo + chunk, N);
  int s = 0;
  for (int i = lo; i < hi; ++i) s += dg[i];
  int lane = t & 63, wid = t >> 6;
  int v = s;                              // wave inclusive scan
  for (int d = 1; d < 64; d <<= 1) {
    int u = __shfl_up(v, d, 64);
    if (lane >= d) v += u;
  }
  if (lane == 63) wsum[wid] = v;
  __syncthreads();
  if (t < 16) {                           // scan the 16 wave totals
    int wv = wsum[t];
    for (int d = 1; d < 16; d <<= 1) {
      int u = __shfl_up(wv, d, 16);
      if (t >= d) wv += u;
    }
    wsum[t] = wv;                         // inclusive
  }
  __syncthreads();
  int waveoff = wid ? wsum[wid - 1] : 0;
  int run = waveoff + (v - s);            // exclusive prefix of this thread's chunk
  for (int i = lo; i < hi; ++i) {
    rs[i] = run; cu[i] = run; run += dg[i];
  }
  if (t == 1023) rs[N] = waveoff + v;     // grand total
}

// FUSED dst+src scatter (R15: was two kernels + inv[] indirection): the same
// thread knows both the dst-CSR slot (pos) and src-CSR slot (j) -> smap[j]=pos.
__global__ void k_scatter(const int* __restrict__ src, const int* __restrict__ dst,
                          int E, int N, int* __restrict__ cursor, int* __restrict__ scursor,
                          int* __restrict__ eid, int* __restrict__ srcc,
                          int* __restrict__ smap) {
  int e = blockIdx.x * blockDim.x + threadIdx.x;
  if (e >= E + N) return;
  int s, d;
  if (e < E) { s = src[e]; d = dst[e]; } else { s = d = e - E; }
  int pos = atomicAdd(&cursor[d], 1);
  eid[pos] = e; srcc[pos] = s;
  int j = atomicAdd(&scursor[s], 1);
  smap[j] = pos;
}

// ---------------- weight prep (MFMA fragment packing) ----------------

// Pack W (both layers) into B-fragment order for mfma_f32_16x16x32_bf16:
// B[k][j]: j = lane&15, k = ks*32 + (lane>>4)*8 + i.
// Flat: Wb[((layer*64 + ct)*2 + ks)*512 + lane*8 + i], ct = 16-col tile.
__global__ void k_prep_w(const float* __restrict__ W1, const float* __restrict__ W2,
                         unsigned short* __restrict__ Wbh, unsigned short* __restrict__ Wbl) {
  int t = blockIdx.x * 256 + threadIdx.x;   // t = ((layer*64+ct)*2+ks)*64+lane
  if (t >= 2 * 64 * 2 * 64) return;
  int lane = t & 63, ks = (t >> 6) & 1, ct = (t >> 7) & 63, layer = t >> 13;
  const float* W = layer ? W2 : W1;
  int col = ct * 16 + (lane & 15);
  int kb = ks * 32 + ((lane >> 4) << 3);
  u16x8 H, L;
#pragma unroll
  for (int i = 0; i < 8; ++i) {
    float v = W[(size_t)(kb + i) * THC + col];
    unsigned short hi = f2bf(v);
    H[i] = hi;
    L[i] = f2bf(v - bf2f(hi));
  }
  *(u16x8*)&Wbh[(size_t)t * 8] = H;
  *(u16x8*)&Wbl[(size_t)t * 8] = L;
}

// FUSED w_e fold + fragment pack (R15: was k_we2 + k_pack_we, two dispatches):
// 1 block x 256 threads; thread t computes its 8 (d,h) dots directly and writes
// the packed B-fragment. Web[(layer*2+ks)*512 + lane*8 + i]: j=lane&15=head,
// k = ks*32 + (lane>>4)*8 + i = d.
__global__ void k_we_pack(const float* __restrict__ We1, const float* __restrict__ ae1,
                          const float* __restrict__ We2, const float* __restrict__ ae2,
                          unsigned short* __restrict__ Webh,
                          unsigned short* __restrict__ Webl) {
  int t = threadIdx.x;               // 256 threads, 1 block
  int lane = t & 63, ks = (t >> 6) & 1, layer = t >> 7;
  const float* We = layer ? We2 : We1;
  const float* ae = layer ? ae2 : ae1;
  int h = lane & 15;
  int kb = ks * 32 + ((lane >> 4) << 3);
  u16x8 H, L;
#pragma unroll
  for (int i = 0; i < 8; ++i) {
    int d = kb + i;
    float s = 0.f;
    for (int c = 0; c < TC; ++c) s += We[(size_t)d * THC + h * TC + c] * ae[h * TC + c];
    unsigned short hi = f2bf(s);
    H[i] = hi;
    L[i] = f2bf(s - bf2f(hi));
  }
  *(u16x8*)&Webh[(size_t)t * 8] = H;
  *(u16x8*)&Webl[(size_t)t * 8] = L;
}

// ---------------- MFMA feature GEMM ----------------

// xp = x @ W via bf16-split (3 MFMA terms: hh + hl + lh; lo*lo ~ 2^-18, dropped).
// Block = 64 rows x 128 cols (head pair), 4 waves; wave w owns rows r0+16w..+16.
// R15: x loaded fp32 directly and hi/lo-split IN REGISTERS (pattern proven in
// k_al_e_mfma) — kills k_prep_x and the xbh/xbl round-trip; identical values.
// No LDS, no barriers. Fused epilogue: al_s/al_d via 16-lane shfl reduce.
// A layout: row=lane&15, k=(lane>>4)*8+i; D: col=lane&15, row=(lane>>4)*4+reg.
__global__ __launch_bounds__(256) void k_matmul_mfma(
    const float* __restrict__ xin,
    const unsigned short* __restrict__ Wbh, const unsigned short* __restrict__ Wbl,
    const float* __restrict__ a_src, const float* __restrict__ a_dst,
    int N, int nrb, float* __restrict__ xp,
    float* __restrict__ al_s, float* __restrict__ al_d) {
  int tid = threadIdx.x;
  // bijective XCD swizzle (measured: keeps FETCH L2-resident, R8/R9)
  int nwg = nrb * 8;
  int wg = blockIdx.x;
  int q = nwg >> 3, rm = nwg & 7;
  int xcd = wg & 7, off = wg >> 3;
  int g = (xcd < rm ? xcd * (q + 1) : rm * (q + 1) + (xcd - rm) * q) + off;
  int hp = g & 7;                    // head pair
  int rb = g >> 3;
  int r0 = rb * 64;
  int w = tid >> 6, l = tid & 63;

  int arow = r0 + w * 16 + (l & 15);
  int koff = (l >> 4) << 3;
  float a0[8], a1[8];
  if (arow < N) {
    float4 v0 = *(const float4*)&xin[(size_t)arow * TD + koff];
    float4 v1 = *(const float4*)&xin[(size_t)arow * TD + koff + 4];
    float4 v2 = *(const float4*)&xin[(size_t)arow * TD + 32 + koff];
    float4 v3 = *(const float4*)&xin[(size_t)arow * TD + 32 + koff + 4];
    a0[0] = v0.x; a0[1] = v0.y; a0[2] = v0.z; a0[3] = v0.w;
    a0[4] = v1.x; a0[5] = v1.y; a0[6] = v1.z; a0[7] = v1.w;
    a1[0] = v2.x; a1[1] = v2.y; a1[2] = v2.z; a1[3] = v2.w;
    a1[4] = v3.x; a1[5] = v3.y; a1[6] = v3.z; a1[7] = v3.w;
  } else {
#pragma unroll
    for (int i = 0; i < 8; ++i) { a0[i] = 0.f; a1[i] = 0.f; }
  }
  bf16x8 ah0, alo0, ah1, alo1;
#pragma unroll
  for (int i = 0; i < 8; ++i) {
    unsigned short h0 = f2bf(a0[i]);
    ah0[i] = (short)h0; alo0[i] = (short)f2bf(a0[i] - bf2f(h0));
    unsigned short h1 = f2bf(a1[i]);
    ah1[i] = (short)h1; alo1[i] = (short)f2bf(a1[i] - bf2f(h1));
  }

  f32x4 acc[8];
  int ct0 = hp * 8;
#pragma unroll
  for (int nt = 0; nt < 8; ++nt) {
    size_t base = ((size_t)(ct0 + nt) * 2) * 512 + l * 8;
    bf16x8 bh0 = *(const bf16x8*)&Wbh[base];
    bf16x8 bh1 = *(const bf16x8*)&Wbh[base + 512];
    bf16x8 bl0 = *(const bf16x8*)&Wbl[base];
    bf16x8 bl1 = *(const bf16x8*)&Wbl[base + 512];
    f32x4 a = {0.f, 0.f, 0.f, 0.f};
    a = __builtin_amdgcn_mfma_f32_16x16x32_bf16(ah0, bh0, a, 0, 0, 0);
    a = __builtin_amdgcn_mfma_f32_16x16x32_bf16(ah1, bh1, a, 0, 0, 0);
    a = __builtin_amdgcn_mfma_f32_16x16x32_bf16(ah0, bl0, a, 0, 0, 0);
    a = __builtin_amdgcn_mfma_f32_16x16x32_bf16(ah1, bl1, a, 0, 0, 0);
    a = __builtin_amdgcn_mfma_f32_16x16x32_bf16(alo0, bh0, a, 0, 0, 0);
    a = __builtin_amdgcn_mfma_f32_16x16x32_bf16(alo1, bh1, a, 0, 0, 0);
    acc[nt] = a;
  }

  int rbase = r0 + w * 16 + ((l >> 4) << 2);
  int cl = l & 15;
#pragma unroll
  for (int nt = 0; nt < 8; ++nt) {
    int colg = hp * 128 + nt * 16 + cl;
#pragma unroll
    for (int r = 0; r < 4; ++r) {
      int rowg = rbase + r;
      if (rowg < N) xp[(size_t)rowg * THC + colg] = acc[nt][r];
    }
  }
  // fused al_s/al_d
#pragma unroll
  for (int hh = 0; hh < 2; ++hh) {
    int h = 2 * hp + hh;
    float as0 = a_src[h * TC + 0 * 16 + cl], as1 = a_src[h * TC + 1 * 16 + cl];
    float as2 = a_src[h * TC + 2 * 16 + cl], as3 = a_src[h * TC + 3 * 16 + cl];
    float ad0 = a_dst[h * TC + 0 * 16 + cl], ad1 = a_dst[h * TC + 1 * 16 + cl];
    float ad2 = a_dst[h * TC + 2 * 16 + cl], ad3 = a_dst[h * TC + 3 * 16 + cl];
#pragma unroll
    for (int r = 0; r < 4; ++r) {
      float ps = acc[hh * 4 + 0][r] * as0 + acc[hh * 4 + 1][r] * as1 +
                 acc[hh * 4 + 2][r] * as2 + acc[hh * 4 + 3][r] * as3;
      float pd = acc[hh * 4 + 0][r] * ad0 + acc[hh * 4 + 1][r] * ad1 +
                 acc[hh * 4 + 2][r] * ad2 + acc[hh * 4 + 3][r] * ad3;
      for (int m = 8; m >= 1; m >>= 1) {
        ps += __shfl_xor(ps, m, 16);
        pd += __shfl_xor(pd, m, 16);
      }
      int rowg = rbase + r;
      if (cl == 0 && rowg < N) { al_s[rowg * TH + h] = ps; al_d[rowg * TH + h] = pd; }
    }
  }
}

// ---------------- edge-logit GEMM (MFMA) ----------------

// ale[e,h] for BOTH layers in one MFMA pass: [E,64] @ [64,16] x 2 layers.
// Wave handles 16 edges; A loaded fp32 from ea, bf16-split in registers;
// 12 MFMA/wave; no LDS/barriers. (R14: LDS version was 44.8us, 6.4M conflicts.)
__global__ __launch_bounds__(256) void k_al_e_mfma(
    const float* __restrict__ ea,
    const unsigned short* __restrict__ Webh, const unsigned short* __restrict__ Webl,
    int E, float* __restrict__ ale1, float* __restrict__ ale2) {
  int tid = threadIdx.x;
  int w = tid >> 6, l = tid & 63;
  int e0 = blockIdx.x * 64 + w * 16;
  int arow = e0 + (l & 15);
  int koff = (l >> 4) << 3;
  float a0[8], a1[8];
  if (arow < E) {
    float4 v0 = *(const float4*)&ea[(size_t)arow * TD + koff];
    float4 v1 = *(const float4*)&ea[(size_t)arow * TD + koff + 4];
    float4 v2 = *(const float4*)&ea[(size_t)arow * TD + 32 + koff];
    float4 v3 = *(const float4*)&ea[(size_t)arow * TD + 32 + koff + 4];
    a0[0] = v0.x; a0[1] = v0.y; a0[2] = v0.z; a0[3] = v0.w;
    a0[4] = v1.x; a0[5] = v1.y; a0[6] = v1.z; a0[7] = v1.w;
    a1[0] = v2.x; a1[1] = v2.y; a1[2] = v2.z; a1[3] = v2.w;
    a1[4] = v3.x; a1[5] = v3.y; a1[6] = v3.z; a1[7] = v3.w;
  } else {
#pragma unroll
    for (int i = 0; i < 8; ++i) { a0[i] = 0.f; a1[i] = 0.f; }
  }
  bf16x8 ah0, alo0, ah1, alo1;
#pragma unroll
  for (int i = 0; i < 8; ++i) {
    unsigned short h0 = f2bf(a0[i]);
    ah0[i] = (short)h0; alo0[i] = (short)f2bf(a0[i] - bf2f(h0));
    unsigned short h1 = f2bf(a1[i]);
    ah1[i] = (short)h1; alo1[i] = (short)f2bf(a1[i] - bf2f(h1));
  }

  f32x4 acc0 = {0.f, 0.f, 0.f, 0.f}, acc1 = {0.f, 0.f, 0.f, 0.f};
#pragma unroll
  for (int ks = 0; ks < 2; ++ks) {
    bf16x8 ah = ks ? ah1 : ah0;
    bf16x8 alo = ks ? alo1 : alo0;
    size_t b0 = (size_t)ks * 512 + l * 8;          // layer 0
    size_t b1 = (size_t)(2 + ks) * 512 + l * 8;    // layer 1
    bf16x8 bh_0 = *(const bf16x8*)&Webh[b0];
    bf16x8 bl_0 = *(const bf16x8*)&Webl[b0];
    bf16x8 bh_1 = *(const bf16x8*)&Webh[b1];
    bf16x8 bl_1 = *(const bf16x8*)&Webl[b1];
    acc0 = __builtin_amdgcn_mfma_f32_16x16x32_bf16(ah, bh_0, acc0, 0, 0, 0);
    acc0 = __builtin_amdgcn_mfma_f32_16x16x32_bf16(ah, bl_0, acc0, 0, 0, 0);
    acc0 = __builtin_amdgcn_mfma_f32_16x16x32_bf16(alo, bh_0, acc0, 0, 0, 0);
    acc1 = __builtin_amdgcn_mfma_f32_16x16x32_bf16(ah, bh_1, acc1, 0, 0, 0);
    acc1 = __builtin_amdgcn_mfma_f32_16x16x32_bf16(ah, bl_1, acc1, 0, 0, 0);
    acc1 = __builtin_amdgcn_mfma_f32_16x16x32_bf16(alo, bh_1, acc1, 0, 0, 0);
  }

  int rbase = e0 + ((l >> 4) << 2);
  int h = l & 15;
#pragma unroll
  for (int r = 0; r < 4; ++r) {
    int e = rbase + r;
    if (e < E) {
      ale1[(size_t)e * TH + h] = acc0[r];
      ale2[(size_t)e * TH + h] = acc1[r];
    }
  }
}

// ---------------- attention / aggregation (measured-good) -------

// one WAVE per dst node, barrier/LDS-free (measured win R9): lane = h + 16*slot.
__global__ __launch_bounds__(256) void k_att(
    const float* __restrict__ al_s, const float* __restrict__ al_d,
    const float* __restrict__ ale, const int* __restrict__ row_start,
    const int* __restrict__ eid, const int* __restrict__ srcc,
    int E, int N, float* __restrict__ att) {
  int tid = threadIdx.x;
  int n = blockIdx.x * 4 + (tid >> 6);
  if (n >= N) return;
  int lane = tid & 63;
  int h = lane & 15, slot = lane >> 4;
  int beg = row_start[n], end = row_start[n + 1], deg = end - beg;
  float ald = al_d[n * TH + h];

  float a0 = 0.f, a1 = 0.f, a2 = 0.f, a3 = 0.f;
  float asum = 0.f;
  int selfp = -1;
  int cnt = 0;
  for (int p = slot; p < deg; p += 4, ++cnt) {
    int i = beg + p;
    int e = eid[i], s = srcc[i];
    float av = 0.f;
    if (e < E) { av = ale[(size_t)e * TH + h]; asum += av; }
    else selfp = p;
    float a = al_s[s * TH + h] + ald + av;
    if (cnt == 0) a0 = a; else if (cnt == 1) a1 = a;
    else if (cnt == 2) a2 = a; else if (cnt == 3) a3 = a;
  }
  asum += __shfl_xor(asum, 16);
  asum += __shfl_xor(asum, 32);
  float lale = asum / (float)max(deg - 1, 1);

  auto fin = [&](float a, int p) -> float {
    if (p == selfp) a += lale;
    return (a > 0.f) ? a : 0.2f * a;
  };
  auto raw = [&](int p) -> float {
    int i = beg + p;
    int e = eid[i], s = srcc[i];
    float av = (e < E) ? ale[(size_t)e * TH + h] : 0.f;
    return al_s[s * TH + h] + ald + av;
  };

  float mloc = -1e30f;
  cnt = 0;
  for (int p = slot; p < deg; p += 4, ++cnt) {
    float a;
    if      (cnt == 0) { a0 = fin(a0, p); a = a0; }
    else if (cnt == 1) { a1 = fin(a1, p); a = a1; }
    else if (cnt == 2) { a2 = fin(a2, p); a = a2; }
    else if (cnt == 3) { a3 = fin(a3, p); a = a3; }
    else a = fin(raw(p), p);
    mloc = fmaxf(mloc, a);
  }
  mloc = fmaxf(mloc, __shfl_xor(mloc, 16));
  mloc = fmaxf(mloc, __shfl_xor(mloc, 32));

  float dloc = 0.f;
  cnt = 0;
  for (int p = slot; p < deg; p += 4, ++cnt) {
    float a = (cnt == 0) ? a0 : (cnt == 1) ? a1 : (cnt == 2) ? a2 : (cnt == 3) ? a3
              : fin(raw(p), p);
    dloc += expf(a - mloc);
  }
  dloc += __shfl_xor(dloc, 16);
  dloc += __shfl_xor(dloc, 32);
  float dinv = 1.f / (dloc + 1e-16f);

  cnt = 0;
  for (int p = slot; p < deg; p += 4, ++cnt) {
    float a = (cnt == 0) ? a0 : (cnt == 1) ? a1 : (cnt == 2) ? a2 : (cnt == 3) ? a3
              : fin(raw(p), p);
    att[(size_t)(beg + p) * TH + h] = expf(a - mloc) * dinv;
  }
}

// src-major, LDS/barrier-free: one WAVE per src node. R15 layout: lane = channel
// (c = lane, 16 scalar xf regs = full 1024-col row across 64 lanes, NO redundant
// loads — old slot layout read the same 4KB row 4x). Edges serial per wave;
// identical per-channel FMA order -> bit-identical z.
__global__ __launch_bounds__(256) void k_csc_z(const float* __restrict__ xp,
                                               const float* __restrict__ att,
                                               const int* __restrict__ srow,
                                               const int* __restrict__ smap,
                                               int N, float* __restrict__ z) {
  int tid = threadIdx.x;
  int s = blockIdx.x * 4 + (tid >> 6);
  if (s >= N) return;
  int c = tid & 63;
  float xf[16];
#pragma unroll
  for (int h = 0; h < TH; ++h)
    xf[h] = xp[(size_t)s * THC + h * 64 + c];
  int beg = srow[s], end = srow[s + 1];
  for (int j = beg; j < end; ++j) {
    int i = smap[j];
    const float* ar = &att[(size_t)i * TH];
    float4 a0 = *(const float4*)&ar[0];
    float4 a1 = *(const float4*)&ar[4];
    float4 a2 = *(const float4*)&ar[8];
    float4 a3 = *(const float4*)&ar[12];
    float aw[16] = {a0.x, a0.y, a0.z, a0.w, a1.x, a1.y, a1.z, a1.w,
                    a2.x, a2.y, a2.z, a2.w, a3.x, a3.y, a3.z, a3.w};
    float acc = 0.f;
#pragma unroll
    for (int hh = 0; hh < TH; ++hh) acc += aw[hh] * xf[hh];
    z[(size_t)i * 64 + c] = acc;
  }
}

// per-dst: sum contiguous z segment, head-mean + bias + relu.
__global__ __launch_bounds__(256) void k_sum_z(const float* __restrict__ z,
                                               const int* __restrict__ row_start,
                                               const float* __restrict__ bias, int N,
                                               float* __restrict__ out) {
  int tid = threadIdx.x;
  int n = blockIdx.x * 16 + (tid >> 4);
  int c4 = (tid & 15) * 4;
  if (n >= N) return;
  int beg = row_start[n], end = row_start[n + 1];
  float4 acc = make_float4(0.f, 0.f, 0.f, 0.f);
  for (int i = beg; i < end; ++i) {
    float4 v = *(const float4*)&z[(size_t)i * 64 + c4];
    acc.x += v.x; acc.y += v.y; acc.z += v.z; acc.w += v.w;
  }
  float4 b = *(const float4*)&bias[c4];
  float4 o;
  o.x = fmaxf(acc.x * (1.0f / TH) + b.x, 0.f);
  o.y = fmaxf(acc.y * (1.0f / TH) + b.y, 0.f);
  o.z = fmaxf(acc.z * (1.0f / TH) + b.z, 0.f);
  o.w = fmaxf(acc.w * (1.0f / TH) + b.w, 0.f);
  *(float4*)&out[(size_t)n * 64 + c4] = o;
}

// ---------------- launch ----------------

extern "C" void kernel_launch(void* const* d_in, const int* in_sizes, int n_in,
                              void* d_out, int out_size, void* d_ws, size_t ws_size,
                              hipStream_t stream) {
  const float* x   = (const float*)d_in[0];
  const int*   ei  = (const int*)d_in[1];
  const float* ea  = (const float*)d_in[2];
  const float* W1  = (const float*)d_in[3];
  const float* as1 = (const float*)d_in[4];
  const float* ad1 = (const float*)d_in[5];
  const float* We1 = (const float*)d_in[6];
  const float* ae1 = (const float*)d_in[7];
  const float* b1  = (const float*)d_in[8];
  const float* W2  = (const float*)d_in[9];
  const float* as2 = (const float*)d_in[10];
  const float* ad2 = (const float*)d_in[11];
  const float* We2 = (const float*)d_in[12];
  const float* ae2 = (const float*)d_in[13];
  const float* b2  = (const float*)d_in[14];

  const int N  = in_sizes[0] / TD;   // 20000
  const int E  = in_sizes[1] / 2;    // 100000
  const int EN = E + N;              // 120000 (with self-loops)
  const int* srcA = ei;
  const int* dstA = ei + E;

  char* w = (char*)d_ws;
  auto alloc = [&](size_t bytes) {
    char* p = w;
    w += (bytes + 255) & ~(size_t)255;
    return p;
  };
  int*   deg2      = (int*)alloc((size_t)2 * N * 4);      // degd | degs
  int*   degd      = deg2;
  int*   degs      = deg2 + N;
  int*   row_start = (int*)alloc((size_t)(N + 1) * 4);
  int*   srow      = (int*)alloc((size_t)(N + 1) * 4);
  int*   cursor    = (int*)alloc((size_t)N * 4);
  int*   scursor   = (int*)alloc((size_t)N * 4);
  int*   eid       = (int*)alloc((size_t)EN * 4);
  int*   srcc      = (int*)alloc((size_t)EN * 4);
  int*   smap      = (int*)alloc((size_t)EN * 4);
  float* xp        = (float*)alloc((size_t)N * THC * 4);  // 82 MB
  float* al_s      = (float*)alloc((size_t)N * TH * 4);
  float* al_d      = (float*)alloc((size_t)N * TH * 4);
  float* ale1      = (float*)alloc((size_t)E * TH * 4);   // 6.4 MB
  float* ale2      = (float*)alloc((size_t)E * TH * 4);   // 6.4 MB
  float* att       = (float*)alloc((size_t)EN * TH * 4);  // 7.7 MB
  float* z         = (float*)alloc((size_t)EN * TC * 4);  // 30.7 MB
  unsigned short* Wbh = (unsigned short*)alloc((size_t)2 * 64 * 2 * 64 * 8 * 2);
  unsigned short* Wbl = (unsigned short*)alloc((size_t)2 * 64 * 2 * 64 * 8 * 2);
  unsigned short* Webh = (unsigned short*)alloc((size_t)4 * 512 * 2);
  unsigned short* Webl = (unsigned short*)alloc((size_t)4 * 512 * 2);
  float* hbuf      = (float*)ale1;   // overlay: ale1 dead after layer-1 k_att;
                                     // 6.4 MB >= 5.1 MB needed

  // CSR (by dst) + CSC (by src) build, shared by both layers
  hipMemsetAsync(deg2, 0, (size_t)2 * N * 4, stream);
  k_count2<<<(EN + 255) / 256, 256, 0, stream>>>(srcA, dstA, E, N, degd, degs);
  k_scan2<<<2, 1024, 0, stream>>>(degd, N, row_start, cursor, degs, srow, scursor);
  k_scatter<<<(EN + 255) / 256, 256, 0, stream>>>(srcA, dstA, E, N, cursor, scursor,
                                                  eid, srcc, smap);

  // W fragment-pack + edge-attention logits for BOTH layers up-front (MFMA)
  k_prep_w<<<(2 * 64 * 2 * 64 + 255) / 256, 256, 0, stream>>>(W1, W2, Wbh, Wbl);
  k_we_pack<<<1, 256, 0, stream>>>(We1, ae1, We2, ae2, Webh, Webl);
  k_al_e_mfma<<<(E + 63) / 64, 256, 0, stream>>>(ea, Webh, Webl, E, ale1, ale2);

  const int nrb = (N + 63) / 64;     // 313 row blocks (64 rows each)
  const int mmgrid = nrb * 8;        // 2504 blocks (64 rows x 2 heads), XCD-swizzled
  const size_t WBL = 64 * 2 * 64 * 8;  // per-layer Wb elements

  // layer 1
  k_matmul_mfma<<<mmgrid, 256, 0, stream>>>(x, Wbh, Wbl, as1, ad1,
                                            N, nrb, xp, al_s, al_d);
  k_att<<<(N + 3) / 4, 256, 0, stream>>>(al_s, al_d, ale1, row_start, eid, srcc, E, N, att);
  k_csc_z<<<(N + 3) / 4, 256, 0, stream>>>(xp, att, srow, smap, N, z);
  k_sum_z<<<(N + 15) / 16, 256, 0, stream>>>(z, row_start, b1, N, hbuf);

  // layer 2
  k_matmul_mfma<<<mmgrid, 256, 0, stream>>>(hbuf, Wbh + WBL, Wbl + WBL, as2, ad2,
                                            N, nrb, xp, al_s, al_d);
  k_att<<<(N + 3) / 4, 256, 0, stream>>>(al_s, al_d, ale2, row_start, eid, srcc, E, N, att);
  k_csc_z<<<(N + 3) / 4, 256, 0, stream>>>(xp, att, srow, smap, N, z);
  k_sum_z<<<(N + 15) / 16, 256, 0, stream>>>(z, row_start, b2, N, (float*)d_out);
}

// Round 17
// 263.192 us; speedup vs baseline: 1.0493x; 1.0493x over previous
//
#include <hip/hip_runtime.h>

// GAT (2-layer, PyG GATConv semantics) on MI355X — src-major aggregation,
// bf16-split MFMA for BOTH the feature GEMM and the edge-logit GEMM.
// N=20000 nodes, E=100000 edges (+N self-loops), D=64, H=16 heads, C=64 ch/head.
constexpr int TD  = 64;      // input feature dim
constexpr int TH  = 16;      // heads
constexpr int TC  = 64;      // channels per head
constexpr int THC = TH * TC; // 1024

typedef short bf16x8 __attribute__((ext_vector_type(8)));
typedef unsigned short u16x8 __attribute__((ext_vector_type(8)));
typedef float f32x4 __attribute__((ext_vector_type(4)));

static __device__ __forceinline__ unsigned short f2bf(float f) {  // RNE f32->bf16
  unsigned u = __float_as_uint(f);
  u += 0x7FFF + ((u >> 16) & 1);
  return (unsigned short)(u >> 16);
}
static __device__ __forceinline__ float bf2f(unsigned short h) {
  return __uint_as_float(((unsigned)h) << 16);
}

// ---------------- CSR/CSC build (once, shared by both layers) ----------------

__global__ void k_count2(const int* __restrict__ src, const int* __restrict__ dst,
                         int E, int N, int* __restrict__ degd, int* __restrict__ degs) {
  int e = blockIdx.x * blockDim.x + threadIdx.x;
  if (e >= E + N) return;
  int s, d;
  if (e < E) { s = src[e]; d = dst[e]; } else { s = d = e - E; }
  atomicAdd(&degd[d], 1);
  atomicAdd(&degs[s], 1);
}

// hierarchical exclusive scan, 1024 threads (R13->R14: 48us serial -> off top-5).
// block 0: dst-CSR, block 1: src-CSR.
__global__ __launch_bounds__(1024) void k_scan2(
    const int* __restrict__ degd, int N,
    int* __restrict__ row_start, int* __restrict__ cursor,
    const int* __restrict__ degs,
    int* __restrict__ srow, int* __restrict__ scursor) {
  const int* dg = blockIdx.x ? degs : degd;
  int* rs = blockIdx.x ? srow : row_start;
  int* cu = blockIdx.x ? scursor : cursor;
  __shared__ int wsum[16];
  int t = threadIdx.x;
  int chunk = (N + 1023) / 1024;
  int lo = min(t * chunk, N), hi = min(lo + chunk, N);
  int s = 0;
  for (int i = lo; i < hi; ++i) s += dg[i];
  int lane = t & 63, wid = t >> 6;
  int v = s;                              // wave inclusive scan
  for (int d = 1; d < 64; d <<= 1) {
    int u = __shfl_up(v, d, 64);
    if (lane >= d) v += u;
  }
  if (lane == 63) wsum[wid] = v;
  __syncthreads();
  if (t < 16) {                           // scan the 16 wave totals
    int wv = wsum[t];
    for (int d = 1; d < 16; d <<= 1) {
      int u = __shfl_up(wv, d, 16);
      if (t >= d) wv += u;
    }
    wsum[t] = wv;                         // inclusive
  }
  __syncthreads();
  int waveoff = wid ? wsum[wid - 1] : 0;
  int run = waveoff + (v - s);            // exclusive prefix of this thread's chunk
  for (int i = lo; i < hi; ++i) {
    rs[i] = run; cu[i] = run; run += dg[i];
  }
  if (t == 1023) rs[N] = waveoff + v;     // grand total
}

// FUSED dst+src scatter (R15: was two kernels + inv[] indirection): the same
// thread knows both the dst-CSR slot (pos) and src-CSR slot (j) -> smap[j]=pos.
__global__ void k_scatter(const int* __restrict__ src, const int* __restrict__ dst,
                          int E, int N, int* __restrict__ cursor, int* __restrict__ scursor,
                          int* __restrict__ eid, int* __restrict__ srcc,
                          int* __restrict__ smap) {
  int e = blockIdx.x * blockDim.x + threadIdx.x;
  if (e >= E + N) return;
  int s, d;
  if (e < E) { s = src[e]; d = dst[e]; } else { s = d = e - E; }
  int pos = atomicAdd(&cursor[d], 1);
  eid[pos] = e; srcc[pos] = s;
  int j = atomicAdd(&scursor[s], 1);
  smap[j] = pos;
}

// ---------------- weight prep (MFMA fragment packing) ----------------

// Pack W (both layers) into B-fragment order for mfma_f32_16x16x32_bf16:
// B[k][j]: j = lane&15, k = ks*32 + (lane>>4)*8 + i.
// Flat: Wb[((layer*64 + ct)*2 + ks)*512 + lane*8 + i], ct = 16-col tile.
__global__ void k_prep_w(const float* __restrict__ W1, const float* __restrict__ W2,
                         unsigned short* __restrict__ Wbh, unsigned short* __restrict__ Wbl) {
  int t = blockIdx.x * 256 + threadIdx.x;   // t = ((layer*64+ct)*2+ks)*64+lane
  if (t >= 2 * 64 * 2 * 64) return;
  int lane = t & 63, ks = (t >> 6) & 1, ct = (t >> 7) & 63, layer = t >> 13;
  const float* W = layer ? W2 : W1;
  int col = ct * 16 + (lane & 15);
  int kb = ks * 32 + ((lane >> 4) << 3);
  u16x8 H, L;
#pragma unroll
  for (int i = 0; i < 8; ++i) {
    float v = W[(size_t)(kb + i) * THC + col];
    unsigned short hi = f2bf(v);
    H[i] = hi;
    L[i] = f2bf(v - bf2f(hi));
  }
  *(u16x8*)&Wbh[(size_t)t * 8] = H;
  *(u16x8*)&Wbl[(size_t)t * 8] = L;
}

// FUSED w_e fold + fragment pack (R15: was k_we2 + k_pack_we): 1 block x 256 thr;
// thread t computes its 8 (d,h) dots and writes the packed B-fragment.
// Web[(layer*2+ks)*512 + lane*8 + i]: j=lane&15=head, k=ks*32+(lane>>4)*8+i=d.
__global__ void k_we_pack(const float* __restrict__ We1, const float* __restrict__ ae1,
                          const float* __restrict__ We2, const float* __restrict__ ae2,
                          unsigned short* __restrict__ Webh,
                          unsigned short* __restrict__ Webl) {
  int t = threadIdx.x;               // 256 threads, 1 block
  int lane = t & 63, ks = (t >> 6) & 1, layer = t >> 7;
  const float* We = layer ? We2 : We1;
  const float* ae = layer ? ae2 : ae1;
  int h = lane & 15;
  int kb = ks * 32 + ((lane >> 4) << 3);
  u16x8 H, L;
#pragma unroll
  for (int i = 0; i < 8; ++i) {
    int d = kb + i;
    float s = 0.f;
    for (int c = 0; c < TC; ++c) s += We[(size_t)d * THC + h * TC + c] * ae[h * TC + c];
    unsigned short hi = f2bf(s);
    H[i] = hi;
    L[i] = f2bf(s - bf2f(hi));
  }
  *(u16x8*)&Webh[(size_t)t * 8] = H;
  *(u16x8*)&Webl[(size_t)t * 8] = L;
}

// ---------------- MFMA feature GEMM ----------------

// xp = x @ W via bf16-split (3 MFMA terms: hh + hl + lh; lo*lo ~ 2^-18, dropped).
// Block = 64 rows x 128 cols (head pair), 4 waves; wave w owns rows r0+16w..+16.
// x loaded fp32 and hi/lo-split in registers (R16; kills prep_x round-trip).
// No LDS, no barriers. Fused epilogue: al_s/al_d via 16-lane shfl reduce.
// A layout: row=lane&15, k=(lane>>4)*8+i; D: col=lane&15, row=(lane>>4)*4+reg.
__global__ __launch_bounds__(256) void k_matmul_mfma(
    const float* __restrict__ xin,
    const unsigned short* __restrict__ Wbh, const unsigned short* __restrict__ Wbl,
    const float* __restrict__ a_src, const float* __restrict__ a_dst,
    int N, int nrb, float* __restrict__ xp,
    float* __restrict__ al_s, float* __restrict__ al_d) {
  int tid = threadIdx.x;
  // bijective XCD swizzle (measured: keeps FETCH L2-resident, R8/R9)
  int nwg = nrb * 8;
  int wg = blockIdx.x;
  int q = nwg >> 3, rm = nwg & 7;
  int xcd = wg & 7, off = wg >> 3;
  int g = (xcd < rm ? xcd * (q + 1) : rm * (q + 1) + (xcd - rm) * q) + off;
  int hp = g & 7;                    // head pair
  int rb = g >> 3;
  int r0 = rb * 64;
  int w = tid >> 6, l = tid & 63;

  int arow = r0 + w * 16 + (l & 15);
  int koff = (l >> 4) << 3;
  float a0[8], a1[8];
  if (arow < N) {
    float4 v0 = *(const float4*)&xin[(size_t)arow * TD + koff];
    float4 v1 = *(const float4*)&xin[(size_t)arow * TD + koff + 4];
    float4 v2 = *(const float4*)&xin[(size_t)arow * TD + 32 + koff];
    float4 v3 = *(const float4*)&xin[(size_t)arow * TD + 32 + koff + 4];
    a0[0] = v0.x; a0[1] = v0.y; a0[2] = v0.z; a0[3] = v0.w;
    a0[4] = v1.x; a0[5] = v1.y; a0[6] = v1.z; a0[7] = v1.w;
    a1[0] = v2.x; a1[1] = v2.y; a1[2] = v2.z; a1[3] = v2.w;
    a1[4] = v3.x; a1[5] = v3.y; a1[6] = v3.z; a1[7] = v3.w;
  } else {
#pragma unroll
    for (int i = 0; i < 8; ++i) { a0[i] = 0.f; a1[i] = 0.f; }
  }
  bf16x8 ah0, alo0, ah1, alo1;
#pragma unroll
  for (int i = 0; i < 8; ++i) {
    unsigned short h0 = f2bf(a0[i]);
    ah0[i] = (short)h0; alo0[i] = (short)f2bf(a0[i] - bf2f(h0));
    unsigned short h1 = f2bf(a1[i]);
    ah1[i] = (short)h1; alo1[i] = (short)f2bf(a1[i] - bf2f(h1));
  }

  f32x4 acc[8];
  int ct0 = hp * 8;
#pragma unroll
  for (int nt = 0; nt < 8; ++nt) {
    size_t base = ((size_t)(ct0 + nt) * 2) * 512 + l * 8;
    bf16x8 bh0 = *(const bf16x8*)&Wbh[base];
    bf16x8 bh1 = *(const bf16x8*)&Wbh[base + 512];
    bf16x8 bl0 = *(const bf16x8*)&Wbl[base];
    bf16x8 bl1 = *(const bf16x8*)&Wbl[base + 512];
    f32x4 a = {0.f, 0.f, 0.f, 0.f};
    a = __builtin_amdgcn_mfma_f32_16x16x32_bf16(ah0, bh0, a, 0, 0, 0);
    a = __builtin_amdgcn_mfma_f32_16x16x32_bf16(ah1, bh1, a, 0, 0, 0);
    a = __builtin_amdgcn_mfma_f32_16x16x32_bf16(ah0, bl0, a, 0, 0, 0);
    a = __builtin_amdgcn_mfma_f32_16x16x32_bf16(ah1, bl1, a, 0, 0, 0);
    a = __builtin_amdgcn_mfma_f32_16x16x32_bf16(alo0, bh0, a, 0, 0, 0);
    a = __builtin_amdgcn_mfma_f32_16x16x32_bf16(alo1, bh1, a, 0, 0, 0);
    acc[nt] = a;
  }

  int rbase = r0 + w * 16 + ((l >> 4) << 2);
  int cl = l & 15;
#pragma unroll
  for (int nt = 0; nt < 8; ++nt) {
    int colg = hp * 128 + nt * 16 + cl;
#pragma unroll
    for (int r = 0; r < 4; ++r) {
      int rowg = rbase + r;
      if (rowg < N) xp[(size_t)rowg * THC + colg] = acc[nt][r];
    }
  }
  // fused al_s/al_d
#pragma unroll
  for (int hh = 0; hh < 2; ++hh) {
    int h = 2 * hp + hh;
    float as0 = a_src[h * TC + 0 * 16 + cl], as1 = a_src[h * TC + 1 * 16 + cl];
    float as2 = a_src[h * TC + 2 * 16 + cl], as3 = a_src[h * TC + 3 * 16 + cl];
    float ad0 = a_dst[h * TC + 0 * 16 + cl], ad1 = a_dst[h * TC + 1 * 16 + cl];
    float ad2 = a_dst[h * TC + 2 * 16 + cl], ad3 = a_dst[h * TC + 3 * 16 + cl];
#pragma unroll
    for (int r = 0; r < 4; ++r) {
      float ps = acc[hh * 4 + 0][r] * as0 + acc[hh * 4 + 1][r] * as1 +
                 acc[hh * 4 + 2][r] * as2 + acc[hh * 4 + 3][r] * as3;
      float pd = acc[hh * 4 + 0][r] * ad0 + acc[hh * 4 + 1][r] * ad1 +
                 acc[hh * 4 + 2][r] * ad2 + acc[hh * 4 + 3][r] * ad3;
      for (int m = 8; m >= 1; m >>= 1) {
        ps += __shfl_xor(ps, m, 16);
        pd += __shfl_xor(pd, m, 16);
      }
      int rowg = rbase + r;
      if (cl == 0 && rowg < N) { al_s[rowg * TH + h] = ps; al_d[rowg * TH + h] = pd; }
    }
  }
}

// ---------------- edge-logit GEMM (MFMA) ----------------

// ale[e,h] for BOTH layers in one MFMA pass: [E,64] @ [64,16] x 2 layers.
// Wave handles 16 edges; A loaded fp32 from ea, bf16-split in registers;
// 12 MFMA/wave; no LDS/barriers. (R14: LDS version was 44.8us, 6.4M conflicts.)
__global__ __launch_bounds__(256) void k_al_e_mfma(
    const float* __restrict__ ea,
    const unsigned short* __restrict__ Webh, const unsigned short* __restrict__ Webl,
    int E, float* __restrict__ ale1, float* __restrict__ ale2) {
  int tid = threadIdx.x;
  int w = tid >> 6, l = tid & 63;
  int e0 = blockIdx.x * 64 + w * 16;
  int arow = e0 + (l & 15);
  int koff = (l >> 4) << 3;
  float a0[8], a1[8];
  if (arow < E) {
    float4 v0 = *(const float4*)&ea[(size_t)arow * TD + koff];
    float4 v1 = *(const float4*)&ea[(size_t)arow * TD + koff + 4];
    float4 v2 = *(const float4*)&ea[(size_t)arow * TD + 32 + koff];
    float4 v3 = *(const float4*)&ea[(size_t)arow * TD + 32 + koff + 4];
    a0[0] = v0.x; a0[1] = v0.y; a0[2] = v0.z; a0[3] = v0.w;
    a0[4] = v1.x; a0[5] = v1.y; a0[6] = v1.z; a0[7] = v1.w;
    a1[0] = v2.x; a1[1] = v2.y; a1[2] = v2.z; a1[3] = v2.w;
    a1[4] = v3.x; a1[5] = v3.y; a1[6] = v3.z; a1[7] = v3.w;
  } else {
#pragma unroll
    for (int i = 0; i < 8; ++i) { a0[i] = 0.f; a1[i] = 0.f; }
  }
  bf16x8 ah0, alo0, ah1, alo1;
#pragma unroll
  for (int i = 0; i < 8; ++i) {
    unsigned short h0 = f2bf(a0[i]);
    ah0[i] = (short)h0; alo0[i] = (short)f2bf(a0[i] - bf2f(h0));
    unsigned short h1 = f2bf(a1[i]);
    ah1[i] = (short)h1; alo1[i] = (short)f2bf(a1[i] - bf2f(h1));
  }

  f32x4 acc0 = {0.f, 0.f, 0.f, 0.f}, acc1 = {0.f, 0.f, 0.f, 0.f};
#pragma unroll
  for (int ks = 0; ks < 2; ++ks) {
    bf16x8 ah = ks ? ah1 : ah0;
    bf16x8 alo = ks ? alo1 : alo0;
    size_t b0 = (size_t)ks * 512 + l * 8;          // layer 0
    size_t b1 = (size_t)(2 + ks) * 512 + l * 8;    // layer 1
    bf16x8 bh_0 = *(const bf16x8*)&Webh[b0];
    bf16x8 bl_0 = *(const bf16x8*)&Webl[b0];
    bf16x8 bh_1 = *(const bf16x8*)&Webh[b1];
    bf16x8 bl_1 = *(const bf16x8*)&Webl[b1];
    acc0 = __builtin_amdgcn_mfma_f32_16x16x32_bf16(ah, bh_0, acc0, 0, 0, 0);
    acc0 = __builtin_amdgcn_mfma_f32_16x16x32_bf16(ah, bl_0, acc0, 0, 0, 0);
    acc0 = __builtin_amdgcn_mfma_f32_16x16x32_bf16(alo, bh_0, acc0, 0, 0, 0);
    acc1 = __builtin_amdgcn_mfma_f32_16x16x32_bf16(ah, bh_1, acc1, 0, 0, 0);
    acc1 = __builtin_amdgcn_mfma_f32_16x16x32_bf16(ah, bl_1, acc1, 0, 0, 0);
    acc1 = __builtin_amdgcn_mfma_f32_16x16x32_bf16(alo, bh_1, acc1, 0, 0, 0);
  }

  int rbase = e0 + ((l >> 4) << 2);
  int h = l & 15;
#pragma unroll
  for (int r = 0; r < 4; ++r) {
    int e = rbase + r;
    if (e < E) {
      ale1[(size_t)e * TH + h] = acc0[r];
      ale2[(size_t)e * TH + h] = acc1[r];
    }
  }
}

// ---------------- attention / aggregation (measured-good) -------

// one WAVE per dst node, barrier/LDS-free (measured win R9): lane = h + 16*slot.
__global__ __launch_bounds__(256) void k_att(
    const float* __restrict__ al_s, const float* __restrict__ al_d,
    const float* __restrict__ ale, const int* __restrict__ row_start,
    const int* __restrict__ eid, const int* __restrict__ srcc,
    int E, int N, float* __restrict__ att) {
  int tid = threadIdx.x;
  int n = blockIdx.x * 4 + (tid >> 6);
  if (n >= N) return;
  int lane = tid & 63;
  int h = lane & 15, slot = lane >> 4;
  int beg = row_start[n], end = row_start[n + 1], deg = end - beg;
  float ald = al_d[n * TH + h];

  float a0 = 0.f, a1 = 0.f, a2 = 0.f, a3 = 0.f;
  float asum = 0.f;
  int selfp = -1;
  int cnt = 0;
  for (int p = slot; p < deg; p += 4, ++cnt) {
    int i = beg + p;
    int e = eid[i], s = srcc[i];
    float av = 0.f;
    if (e < E) { av = ale[(size_t)e * TH + h]; asum += av; }
    else selfp = p;
    float a = al_s[s * TH + h] + ald + av;
    if (cnt == 0) a0 = a; else if (cnt == 1) a1 = a;
    else if (cnt == 2) a2 = a; else if (cnt == 3) a3 = a;
  }
  asum += __shfl_xor(asum, 16);
  asum += __shfl_xor(asum, 32);
  float lale = asum / (float)max(deg - 1, 1);

  auto fin = [&](float a, int p) -> float {
    if (p == selfp) a += lale;
    return (a > 0.f) ? a : 0.2f * a;
  };
  auto raw = [&](int p) -> float {
    int i = beg + p;
    int e = eid[i], s = srcc[i];
    float av = (e < E) ? ale[(size_t)e * TH + h] : 0.f;
    return al_s[s * TH + h] + ald + av;
  };

  float mloc = -1e30f;
  cnt = 0;
  for (int p = slot; p < deg; p += 4, ++cnt) {
    float a;
    if      (cnt == 0) { a0 = fin(a0, p); a = a0; }
    else if (cnt == 1) { a1 = fin(a1, p); a = a1; }
    else if (cnt == 2) { a2 = fin(a2, p); a = a2; }
    else if (cnt == 3) { a3 = fin(a3, p); a = a3; }
    else a = fin(raw(p), p);
    mloc = fmaxf(mloc, a);
  }
  mloc = fmaxf(mloc, __shfl_xor(mloc, 16));
  mloc = fmaxf(mloc, __shfl_xor(mloc, 32));

  float dloc = 0.f;
  cnt = 0;
  for (int p = slot; p < deg; p += 4, ++cnt) {
    float a = (cnt == 0) ? a0 : (cnt == 1) ? a1 : (cnt == 2) ? a2 : (cnt == 3) ? a3
              : fin(raw(p), p);
    dloc += expf(a - mloc);
  }
  dloc += __shfl_xor(dloc, 16);
  dloc += __shfl_xor(dloc, 32);
  float dinv = 1.f / (dloc + 1e-16f);

  cnt = 0;
  for (int p = slot; p < deg; p += 4, ++cnt) {
    float a = (cnt == 0) ? a0 : (cnt == 1) ? a1 : (cnt == 2) ? a2 : (cnt == 3) ? a3
              : fin(raw(p), p);
    att[(size_t)(beg + p) * TH + h] = expf(a - mloc) * dinv;
  }
}

// src-major, LDS/barrier-free: one WAVE per src node; lane keeps 16-head xp
// slice as float4 (64 VGPR), 4 edge-slots in flight. REVERTED to the R14
// measured-good form — R15's scalar/serial variant cost ~35us (G13 violation:
// scalar dword loads + 4x less edge MLP; the "redundant" loads it removed were
// same-cacheline wave broadcasts, essentially free).
__global__ __launch_bounds__(256) void k_csc_z(const float* __restrict__ xp,
                                               const float* __restrict__ att,
                                               const int* __restrict__ srow,
                                               const int* __restrict__ smap,
                                               int N, float* __restrict__ z) {
  int tid = threadIdx.x;
  int s = blockIdx.x * 4 + (tid >> 6);
  if (s >= N) return;
  int lane = tid & 63;
  int slot = lane >> 4, c4 = (lane & 15) * 4;
  float4 xf[16];
#pragma unroll
  for (int h = 0; h < TH; ++h)
    xf[h] = *(const float4*)&xp[(size_t)s * THC + h * 64 + c4];
  int beg = srow[s], end = srow[s + 1];
  for (int j = beg + slot; j < end; j += 4) {
    int i = smap[j];
    const float* ar = &att[(size_t)i * TH];
    float4 a0 = *(const float4*)&ar[0];
    float4 a1 = *(const float4*)&ar[4];
    float4 a2 = *(const float4*)&ar[8];
    float4 a3 = *(const float4*)&ar[12];
    float aw[16] = {a0.x, a0.y, a0.z, a0.w, a1.x, a1.y, a1.z, a1.w,
                    a2.x, a2.y, a2.z, a2.w, a3.x, a3.y, a3.z, a3.w};
    float4 acc = make_float4(0.f, 0.f, 0.f, 0.f);
#pragma unroll
    for (int hh = 0; hh < TH; ++hh) {
      acc.x += aw[hh] * xf[hh].x; acc.y += aw[hh] * xf[hh].y;
      acc.z += aw[hh] * xf[hh].z; acc.w += aw[hh] * xf[hh].w;
    }
    *(float4*)&z[(size_t)i * 64 + c4] = acc;
  }
}

// per-dst: sum contiguous z segment, head-mean + bias + relu.
__global__ __launch_bounds__(256) void k_sum_z(const float* __restrict__ z,
                                               const int* __restrict__ row_start,
                                               const float* __restrict__ bias, int N,
                                               float* __restrict__ out) {
  int tid = threadIdx.x;
  int n = blockIdx.x * 16 + (tid >> 4);
  int c4 = (tid & 15) * 4;
  if (n >= N) return;
  int beg = row_start[n], end = row_start[n + 1];
  float4 acc = make_float4(0.f, 0.f, 0.f, 0.f);
  for (int i = beg; i < end; ++i) {
    float4 v = *(const float4*)&z[(size_t)i * 64 + c4];
    acc.x += v.x; acc.y += v.y; acc.z += v.z; acc.w += v.w;
  }
  float4 b = *(const float4*)&bias[c4];
  float4 o;
  o.x = fmaxf(acc.x * (1.0f / TH) + b.x, 0.f);
  o.y = fmaxf(acc.y * (1.0f / TH) + b.y, 0.f);
  o.z = fmaxf(acc.z * (1.0f / TH) + b.z, 0.f);
  o.w = fmaxf(acc.w * (1.0f / TH) + b.w, 0.f);
  *(float4*)&out[(size_t)n * 64 + c4] = o;
}

// ---------------- launch ----------------

extern "C" void kernel_launch(void* const* d_in, const int* in_sizes, int n_in,
                              void* d_out, int out_size, void* d_ws, size_t ws_size,
                              hipStream_t stream) {
  const float* x   = (const float*)d_in[0];
  const int*   ei  = (const int*)d_in[1];
  const float* ea  = (const float*)d_in[2];
  const float* W1  = (const float*)d_in[3];
  const float* as1 = (const float*)d_in[4];
  const float* ad1 = (const float*)d_in[5];
  const float* We1 = (const float*)d_in[6];
  const float* ae1 = (const float*)d_in[7];
  const float* b1  = (const float*)d_in[8];
  const float* W2  = (const float*)d_in[9];
  const float* as2 = (const float*)d_in[10];
  const float* ad2 = (const float*)d_in[11];
  const float* We2 = (const float*)d_in[12];
  const float* ae2 = (const float*)d_in[13];
  const float* b2  = (const float*)d_in[14];

  const int N  = in_sizes[0] / TD;   // 20000
  const int E  = in_sizes[1] / 2;    // 100000
  const int EN = E + N;              // 120000 (with self-loops)
  const int* srcA = ei;
  const int* dstA = ei + E;

  char* w = (char*)d_ws;
  auto alloc = [&](size_t bytes) {
    char* p = w;
    w += (bytes + 255) & ~(size_t)255;
    return p;
  };
  int*   deg2      = (int*)alloc((size_t)2 * N * 4);      // degd | degs
  int*   degd      = deg2;
  int*   degs      = deg2 + N;
  int*   row_start = (int*)alloc((size_t)(N + 1) * 4);
  int*   srow      = (int*)alloc((size_t)(N + 1) * 4);
  int*   cursor    = (int*)alloc((size_t)N * 4);
  int*   scursor   = (int*)alloc((size_t)N * 4);
  int*   eid       = (int*)alloc((size_t)EN * 4);
  int*   srcc      = (int*)alloc((size_t)EN * 4);
  int*   smap      = (int*)alloc((size_t)EN * 4);
  float* xp        = (float*)alloc((size_t)N * THC * 4);  // 82 MB
  float* al_s      = (float*)alloc((size_t)N * TH * 4);
  float* al_d      = (float*)alloc((size_t)N * TH * 4);
  float* ale1      = (float*)alloc((size_t)E * TH * 4);   // 6.4 MB
  float* ale2      = (float*)alloc((size_t)E * TH * 4);   // 6.4 MB
  float* att       = (float*)alloc((size_t)EN * TH * 4);  // 7.7 MB
  float* z         = (float*)alloc((size_t)EN * TC * 4);  // 30.7 MB
  unsigned short* Wbh = (unsigned short*)alloc((size_t)2 * 64 * 2 * 64 * 8 * 2);
  unsigned short* Wbl = (unsigned short*)alloc((size_t)2 * 64 * 2 * 64 * 8 * 2);
  unsigned short* Webh = (unsigned short*)alloc((size_t)4 * 512 * 2);
  unsigned short* Webl = (unsigned short*)alloc((size_t)4 * 512 * 2);
  float* hbuf      = (float*)ale1;   // overlay: ale1 dead after layer-1 k_att;
                                     // 6.4 MB >= 5.1 MB needed

  // CSR (by dst) + CSC (by src) build, shared by both layers
  hipMemsetAsync(deg2, 0, (size_t)2 * N * 4, stream);
  k_count2<<<(EN + 255) / 256, 256, 0, stream>>>(srcA, dstA, E, N, degd, degs);
  k_scan2<<<2, 1024, 0, stream>>>(degd, N, row_start, cursor, degs, srow, scursor);
  k_scatter<<<(EN + 255) / 256, 256, 0, stream>>>(srcA, dstA, E, N, cursor, scursor,
                                                  eid, srcc, smap);

  // W fragment-pack + edge-attention logits for BOTH layers up-front (MFMA)
  k_prep_w<<<(2 * 64 * 2 * 64 + 255) / 256, 256, 0, stream>>>(W1, W2, Wbh, Wbl);
  k_we_pack<<<1, 256, 0, stream>>>(We1, ae1, We2, ae2, Webh, Webl);
  k_al_e_mfma<<<(E + 63) / 64, 256, 0, stream>>>(ea, Webh, Webl, E, ale1, ale2);

  const int nrb = (N + 63) / 64;     // 313 row blocks (64 rows each)
  const int mmgrid = nrb * 8;        // 2504 blocks (64 rows x 2 heads), XCD-swizzled
  const size_t WBL = 64 * 2 * 64 * 8;  // per-layer Wb elements

  // layer 1
  k_matmul_mfma<<<mmgrid, 256, 0, stream>>>(x, Wbh, Wbl, as1, ad1,
                                            N, nrb, xp, al_s, al_d);
  k_att<<<(N + 3) / 4, 256, 0, stream>>>(al_s, al_d, ale1, row_start, eid, srcc, E, N, att);
  k_csc_z<<<(N + 3) / 4, 256, 0, stream>>>(xp, att, srow, smap, N, z);
  k_sum_z<<<(N + 15) / 16, 256, 0, stream>>>(z, row_start, b1, N, hbuf);

  // layer 2
  k_matmul_mfma<<<mmgrid, 256, 0, stream>>>(hbuf, Wbh + WBL, Wbl + WBL, as2, ad2,
                                            N, nrb, xp, al_s, al_d);
  k_att<<<(N + 3) / 4, 256, 0, stream>>>(al_s, al_d, ale2, row_start, eid, srcc, E, N, att);
  k_csc_z<<<(N + 3) / 4, 256, 0, stream>>>(xp, att, srow, smap, N, z);
  k_sum_z<<<(N + 15) / 16, 256, 0, stream>>>(z, row_start, b2, N, (float*)d_out);
}

// Round 18
// 240.116 us; speedup vs baseline: 1.1501x; 1.0961x over previous
//
#include <hip/hip_runtime.h>

// GAT (2-layer, PyG GATConv semantics) on MI355X — src-major aggregation,
// bf16-split MFMA for BOTH the feature GEMM and the edge-logit GEMM.
// This is the verbatim measured-best source (240.9 us, round-15 bench).
// N=20000 nodes, E=100000 edges (+N self-loops), D=64, H=16 heads, C=64 ch/head.
constexpr int TD  = 64;      // input feature dim
constexpr int TH  = 16;      // heads
constexpr int TC  = 64;      // channels per head
constexpr int THC = TH * TC; // 1024

typedef short bf16x8 __attribute__((ext_vector_type(8)));
typedef unsigned short u16x8 __attribute__((ext_vector_type(8)));
typedef float f32x4 __attribute__((ext_vector_type(4)));

static __device__ __forceinline__ unsigned short f2bf(float f) {  // RNE f32->bf16
  unsigned u = __float_as_uint(f);
  u += 0x7FFF + ((u >> 16) & 1);
  return (unsigned short)(u >> 16);
}
static __device__ __forceinline__ float bf2f(unsigned short h) {
  return __uint_as_float(((unsigned)h) << 16);
}

// ---------------- CSR/CSC build (once, shared by both layers) ----------------

__global__ void k_count2(const int* __restrict__ src, const int* __restrict__ dst,
                         int E, int N, int* __restrict__ degd, int* __restrict__ degs) {
  int e = blockIdx.x * blockDim.x + threadIdx.x;
  if (e >= E + N) return;
  int s, d;
  if (e < E) { s = src[e]; d = dst[e]; } else { s = d = e - E; }
  atomicAdd(&degd[d], 1);
  atomicAdd(&degs[s], 1);
}

// hierarchical exclusive scan, 1024 threads (R13: serial version was 48 us, #1
// kernel — latency-bound at 2 blocks; this is ~4 us). block 0: dst, block 1: src.
__global__ __launch_bounds__(1024) void k_scan2(
    const int* __restrict__ degd, int N,
    int* __restrict__ row_start, int* __restrict__ cursor,
    const int* __restrict__ degs,
    int* __restrict__ srow, int* __restrict__ scursor) {
  const int* dg = blockIdx.x ? degs : degd;
  int* rs = blockIdx.x ? srow : row_start;
  int* cu = blockIdx.x ? scursor : cursor;
  __shared__ int wsum[16];
  int t = threadIdx.x;
  int chunk = (N + 1023) / 1024;
  int lo = min(t * chunk, N), hi = min(lo + chunk, N);
  int s = 0;
  for (int i = lo; i < hi; ++i) s += dg[i];
  int lane = t & 63, wid = t >> 6;
  int v = s;                              // wave inclusive scan
  for (int d = 1; d < 64; d <<= 1) {
    int u = __shfl_up(v, d, 64);
    if (lane >= d) v += u;
  }
  if (lane == 63) wsum[wid] = v;
  __syncthreads();
  if (t < 16) {                           // scan the 16 wave totals
    int wv = wsum[t];
    for (int d = 1; d < 16; d <<= 1) {
      int u = __shfl_up(wv, d, 16);
      if (t >= d) wv += u;
    }
    wsum[t] = wv;                         // inclusive
  }
  __syncthreads();
  int waveoff = wid ? wsum[wid - 1] : 0;
  int run = waveoff + (v - s);            // exclusive prefix of this thread's chunk
  for (int i = lo; i < hi; ++i) {
    rs[i] = run; cu[i] = run; run += dg[i];
  }
  if (t == 1023) rs[N] = waveoff + v;     // grand total
}

__global__ void k_scatter_dst(const int* __restrict__ src, const int* __restrict__ dst,
                              int E, int N, int* __restrict__ cursor,
                              int* __restrict__ eid, int* __restrict__ srcc,
                              int* __restrict__ inv) {
  int e = blockIdx.x * blockDim.x + threadIdx.x;
  if (e >= E + N) return;
  int s, d;
  if (e < E) { s = src[e]; d = dst[e]; } else { s = d = e - E; }
  int pos = atomicAdd(&cursor[d], 1);
  eid[pos] = e; srcc[pos] = s; inv[e] = pos;
}

__global__ void k_scatter_src(const int* __restrict__ src, int E, int N,
                              int* __restrict__ scursor, const int* __restrict__ inv,
                              int* __restrict__ smap) {
  int e = blockIdx.x * blockDim.x + threadIdx.x;
  if (e >= E + N) return;
  int s = (e < E) ? src[e] : (e - E);
  int j = atomicAdd(&scursor[s], 1);
  smap[j] = inv[e];
}

// ---------------- bf16-split prep ----------------

// Pack W (both layers) into B-fragment order for mfma_f32_16x16x32_bf16:
// B[k][j]: j = lane&15, k = ks*32 + (lane>>4)*8 + i.
// Flat: Wb[((layer*64 + ct)*2 + ks)*512 + lane*8 + i], ct = 16-col tile.
__global__ void k_prep_w(const float* __restrict__ W1, const float* __restrict__ W2,
                         unsigned short* __restrict__ Wbh, unsigned short* __restrict__ Wbl) {
  int t = blockIdx.x * 256 + threadIdx.x;   // t = ((layer*64+ct)*2+ks)*64+lane
  if (t >= 2 * 64 * 2 * 64) return;
  int lane = t & 63, ks = (t >> 6) & 1, ct = (t >> 7) & 63, layer = t >> 13;
  const float* W = layer ? W2 : W1;
  int col = ct * 16 + (lane & 15);
  int kb = ks * 32 + ((lane >> 4) << 3);
  u16x8 H, L;
#pragma unroll
  for (int i = 0; i < 8; ++i) {
    float v = W[(size_t)(kb + i) * THC + col];
    unsigned short hi = f2bf(v);
    H[i] = hi;
    L[i] = f2bf(v - bf2f(hi));
  }
  *(u16x8*)&Wbh[(size_t)t * 8] = H;
  *(u16x8*)&Wbl[(size_t)t * 8] = L;
}

// Split input rows into bf16 hi/lo, row-major [Npad][64]; pad rows zero.
// (Only needed for layer-1 input x; layer-2 split is fused into k_sum_z.)
__global__ __launch_bounds__(256) void k_prep_x(const float* __restrict__ xin, int N, int Npad,
                                                unsigned short* __restrict__ xbh,
                                                unsigned short* __restrict__ xbl) {
  int t = blockIdx.x * 256 + threadIdx.x;   // one 8-elem chunk
  if (t >= Npad * 8) return;
  int row = t >> 3, c8 = (t & 7) * 8;
  u16x8 H = {0, 0, 0, 0, 0, 0, 0, 0}, L = {0, 0, 0, 0, 0, 0, 0, 0};
  if (row < N) {
    float4 v0 = *(const float4*)&xin[(size_t)row * TD + c8];
    float4 v1 = *(const float4*)&xin[(size_t)row * TD + c8 + 4];
    float v[8] = {v0.x, v0.y, v0.z, v0.w, v1.x, v1.y, v1.z, v1.w};
#pragma unroll
    for (int i = 0; i < 8; ++i) {
      unsigned short hi = f2bf(v[i]);
      H[i] = hi;
      L[i] = f2bf(v[i] - bf2f(hi));
    }
  }
  *(u16x8*)&xbh[(size_t)row * TD + c8] = H;
  *(u16x8*)&xbl[(size_t)row * TD + c8] = L;
}

// ---------------- MFMA feature GEMM ----------------

// xp = x @ W via bf16-split (3 MFMA terms: hh + hl + lh; lo*lo ~ 2^-18, dropped).
// Block = 64 rows x 128 cols (head pair), 4 waves; wave w owns rows r0+16w..+16.
// No LDS, no barriers. Fused epilogue: al_s/al_d via 16-lane shfl reduce.
// D layout (m89-verified): col = lane&15, row = (lane>>4)*4 + reg.
__global__ __launch_bounds__(256) void k_matmul_mfma(
    const unsigned short* __restrict__ xbh, const unsigned short* __restrict__ xbl,
    const unsigned short* __restrict__ Wbh, const unsigned short* __restrict__ Wbl,
    const float* __restrict__ a_src, const float* __restrict__ a_dst,
    int N, int nrb, float* __restrict__ xp,
    float* __restrict__ al_s, float* __restrict__ al_d) {
  int tid = threadIdx.x;
  // bijective XCD swizzle (measured: keeps FETCH L2-resident, R8/R9)
  int nwg = nrb * 8;
  int wg = blockIdx.x;
  int q = nwg >> 3, rm = nwg & 7;
  int xcd = wg & 7, off = wg >> 3;
  int g = (xcd < rm ? xcd * (q + 1) : rm * (q + 1) + (xcd - rm) * q) + off;
  int hp = g & 7;                    // head pair
  int rb = g >> 3;
  int r0 = rb * 64;
  int w = tid >> 6, l = tid & 63;

  int arow = r0 + w * 16 + (l & 15);
  const unsigned short* xh = xbh + (size_t)arow * TD + ((l >> 4) << 3);
  const unsigned short* xl = xbl + (size_t)arow * TD + ((l >> 4) << 3);
  bf16x8 ah0 = *(const bf16x8*)xh;
  bf16x8 ah1 = *(const bf16x8*)(xh + 32);
  bf16x8 alo0 = *(const bf16x8*)xl;
  bf16x8 alo1 = *(const bf16x8*)(xl + 32);

  f32x4 acc[8];
  int ct0 = hp * 8;
#pragma unroll
  for (int nt = 0; nt < 8; ++nt) {
    size_t base = ((size_t)(ct0 + nt) * 2) * 512 + l * 8;
    bf16x8 bh0 = *(const bf16x8*)&Wbh[base];
    bf16x8 bh1 = *(const bf16x8*)&Wbh[base + 512];
    bf16x8 bl0 = *(const bf16x8*)&Wbl[base];
    bf16x8 bl1 = *(const bf16x8*)&Wbl[base + 512];
    f32x4 a = {0.f, 0.f, 0.f, 0.f};
    a = __builtin_amdgcn_mfma_f32_16x16x32_bf16(ah0, bh0, a, 0, 0, 0);
    a = __builtin_amdgcn_mfma_f32_16x16x32_bf16(ah1, bh1, a, 0, 0, 0);
    a = __builtin_amdgcn_mfma_f32_16x16x32_bf16(ah0, bl0, a, 0, 0, 0);
    a = __builtin_amdgcn_mfma_f32_16x16x32_bf16(ah1, bl1, a, 0, 0, 0);
    a = __builtin_amdgcn_mfma_f32_16x16x32_bf16(alo0, bh0, a, 0, 0, 0);
    a = __builtin_amdgcn_mfma_f32_16x16x32_bf16(alo1, bh1, a, 0, 0, 0);
    acc[nt] = a;
  }

  int rbase = r0 + w * 16 + ((l >> 4) << 2);
  int cl = l & 15;
#pragma unroll
  for (int nt = 0; nt < 8; ++nt) {
    int colg = hp * 128 + nt * 16 + cl;
#pragma unroll
    for (int r = 0; r < 4; ++r) {
      int rowg = rbase + r;
      if (rowg < N) xp[(size_t)rowg * THC + colg] = acc[nt][r];
    }
  }
  // fused al_s/al_d
#pragma unroll
  for (int hh = 0; hh < 2; ++hh) {
    int h = 2 * hp + hh;
    float as0 = a_src[h * TC + 0 * 16 + cl], as1 = a_src[h * TC + 1 * 16 + cl];
    float as2 = a_src[h * TC + 2 * 16 + cl], as3 = a_src[h * TC + 3 * 16 + cl];
    float ad0 = a_dst[h * TC + 0 * 16 + cl], ad1 = a_dst[h * TC + 1 * 16 + cl];
    float ad2 = a_dst[h * TC + 2 * 16 + cl], ad3 = a_dst[h * TC + 3 * 16 + cl];
#pragma unroll
    for (int r = 0; r < 4; ++r) {
      float ps = acc[hh * 4 + 0][r] * as0 + acc[hh * 4 + 1][r] * as1 +
                 acc[hh * 4 + 2][r] * as2 + acc[hh * 4 + 3][r] * as3;
      float pd = acc[hh * 4 + 0][r] * ad0 + acc[hh * 4 + 1][r] * ad1 +
                 acc[hh * 4 + 2][r] * ad2 + acc[hh * 4 + 3][r] * ad3;
      for (int m = 8; m >= 1; m >>= 1) {
        ps += __shfl_xor(ps, m, 16);
        pd += __shfl_xor(pd, m, 16);
      }
      int rowg = rbase + r;
      if (cl == 0 && rowg < N) { al_s[rowg * TH + h] = ps; al_d[rowg * TH + h] = pd; }
    }
  }
}

// ---------------- edge-logit GEMM (MFMA) ----------------

// w_e for BOTH layers: w_e[layer][d][h] = sum_c We[d, h*64+c] * a_e[h,c]
__global__ void k_we2(const float* __restrict__ We1, const float* __restrict__ ae1,
                      const float* __restrict__ We2, const float* __restrict__ ae2,
                      float* __restrict__ w_e) {
  int t = blockIdx.x * blockDim.x + threadIdx.x;
  if (t >= 2 * TD * TH) return;
  int layer = t >> 10, tt = t & 1023;
  int d = tt >> 4, h = tt & 15;
  const float* We = layer ? We2 : We1;
  const float* ae = layer ? ae2 : ae1;
  float s = 0.f;
  for (int c = 0; c < TC; ++c) s += We[(size_t)d * THC + h * TC + c] * ae[h * TC + c];
  w_e[t] = s;
}

// pack w_e into B-fragment order (bf16 hi/lo): Web[(layer*2+ks)*512 + lane*8 + i],
// col j = lane&15 = head, k = ks*32 + (lane>>4)*8 + i = d.
__global__ void k_pack_we(const float* __restrict__ w_e,
                          unsigned short* __restrict__ Webh,
                          unsigned short* __restrict__ Webl) {
  int t = threadIdx.x;               // 256 threads, 1 block
  int lane = t & 63, ks = (t >> 6) & 1, layer = t >> 7;
  int h = lane & 15;
  int kb = ks * 32 + ((lane >> 4) << 3);
  u16x8 H, L;
#pragma unroll
  for (int i = 0; i < 8; ++i) {
    float v = w_e[layer * (TD * TH) + (kb + i) * TH + h];
    unsigned short hi = f2bf(v);
    H[i] = hi;
    L[i] = f2bf(v - bf2f(hi));
  }
  *(u16x8*)&Webh[(size_t)t * 8] = H;
  *(u16x8*)&Webl[(size_t)t * 8] = L;
}

// ale[e,h] for BOTH layers in one MFMA pass: [E,64] @ [64,16] x 2 layers.
// Wave handles 16 edges; A loaded fp32 from ea, bf16-split in registers
// (same verified layout as k_matmul_mfma); 12 MFMA/wave; no LDS/barriers.
// R14: LDS version was 44.8 us with 6.4M bank conflicts; this is BW-bound ~7 us.
__global__ __launch_bounds__(256) void k_al_e_mfma(
    const float* __restrict__ ea,
    const unsigned short* __restrict__ Webh, const unsigned short* __restrict__ Webl,
    int E, float* __restrict__ ale1, float* __restrict__ ale2) {
  int tid = threadIdx.x;
  int w = tid >> 6, l = tid & 63;
  int e0 = blockIdx.x * 64 + w * 16;
  int arow = e0 + (l & 15);
  int koff = (l >> 4) << 3;
  float a0[8], a1[8];
  if (arow < E) {
    float4 v0 = *(const float4*)&ea[(size_t)arow * TD + koff];
    float4 v1 = *(const float4*)&ea[(size_t)arow * TD + koff + 4];
    float4 v2 = *(const float4*)&ea[(size_t)arow * TD + 32 + koff];
    float4 v3 = *(const float4*)&ea[(size_t)arow * TD + 32 + koff + 4];
    a0[0] = v0.x; a0[1] = v0.y; a0[2] = v0.z; a0[3] = v0.w;
    a0[4] = v1.x; a0[5] = v1.y; a0[6] = v1.z; a0[7] = v1.w;
    a1[0] = v2.x; a1[1] = v2.y; a1[2] = v2.z; a1[3] = v2.w;
    a1[4] = v3.x; a1[5] = v3.y; a1[6] = v3.z; a1[7] = v3.w;
  } else {
#pragma unroll
    for (int i = 0; i < 8; ++i) { a0[i] = 0.f; a1[i] = 0.f; }
  }
  bf16x8 ah0, alo0, ah1, alo1;
#pragma unroll
  for (int i = 0; i < 8; ++i) {
    unsigned short h0 = f2bf(a0[i]);
    ah0[i] = (short)h0; alo0[i] = (short)f2bf(a0[i] - bf2f(h0));
    unsigned short h1 = f2bf(a1[i]);
    ah1[i] = (short)h1; alo1[i] = (short)f2bf(a1[i] - bf2f(h1));
  }

  f32x4 acc0 = {0.f, 0.f, 0.f, 0.f}, acc1 = {0.f, 0.f, 0.f, 0.f};
#pragma unroll
  for (int ks = 0; ks < 2; ++ks) {
    bf16x8 ah = ks ? ah1 : ah0;
    bf16x8 alo = ks ? alo1 : alo0;
    size_t b0 = (size_t)ks * 512 + l * 8;          // layer 0
    size_t b1 = (size_t)(2 + ks) * 512 + l * 8;    // layer 1
    bf16x8 bh_0 = *(const bf16x8*)&Webh[b0];
    bf16x8 bl_0 = *(const bf16x8*)&Webl[b0];
    bf16x8 bh_1 = *(const bf16x8*)&Webh[b1];
    bf16x8 bl_1 = *(const bf16x8*)&Webl[b1];
    acc0 = __builtin_amdgcn_mfma_f32_16x16x32_bf16(ah, bh_0, acc0, 0, 0, 0);
    acc0 = __builtin_amdgcn_mfma_f32_16x16x32_bf16(ah, bl_0, acc0, 0, 0, 0);
    acc0 = __builtin_amdgcn_mfma_f32_16x16x32_bf16(alo, bh_0, acc0, 0, 0, 0);
    acc1 = __builtin_amdgcn_mfma_f32_16x16x32_bf16(ah, bh_1, acc1, 0, 0, 0);
    acc1 = __builtin_amdgcn_mfma_f32_16x16x32_bf16(ah, bl_1, acc1, 0, 0, 0);
    acc1 = __builtin_amdgcn_mfma_f32_16x16x32_bf16(alo, bh_1, acc1, 0, 0, 0);
  }

  int rbase = e0 + ((l >> 4) << 2);
  int h = l & 15;
#pragma unroll
  for (int r = 0; r < 4; ++r) {
    int e = rbase + r;
    if (e < E) {
      ale1[(size_t)e * TH + h] = acc0[r];
      ale2[(size_t)e * TH + h] = acc1[r];
    }
  }
}

// ---------------- attention / aggregation (measured-good) -------

// one WAVE per dst node, barrier/LDS-free (measured win R9): lane = h + 16*slot.
__global__ __launch_bounds__(256) void k_att(
    const float* __restrict__ al_s, const float* __restrict__ al_d,
    const float* __restrict__ ale, const int* __restrict__ row_start,
    const int* __restrict__ eid, const int* __restrict__ srcc,
    int E, int N, float* __restrict__ att) {
  int tid = threadIdx.x;
  int n = blockIdx.x * 4 + (tid >> 6);
  if (n >= N) return;
  int lane = tid & 63;
  int h = lane & 15, slot = lane >> 4;
  int beg = row_start[n], end = row_start[n + 1], deg = end - beg;
  float ald = al_d[n * TH + h];

  float a0 = 0.f, a1 = 0.f, a2 = 0.f, a3 = 0.f;
  float asum = 0.f;
  int selfp = -1;
  int cnt = 0;
  for (int p = slot; p < deg; p += 4, ++cnt) {
    int i = beg + p;
    int e = eid[i], s = srcc[i];
    float av = 0.f;
    if (e < E) { av = ale[(size_t)e * TH + h]; asum += av; }
    else selfp = p;
    float a = al_s[s * TH + h] + ald + av;
    if (cnt == 0) a0 = a; else if (cnt == 1) a1 = a;
    else if (cnt == 2) a2 = a; else if (cnt == 3) a3 = a;
  }
  asum += __shfl_xor(asum, 16);
  asum += __shfl_xor(asum, 32);
  float lale = asum / (float)max(deg - 1, 1);

  auto fin = [&](float a, int p) -> float {
    if (p == selfp) a += lale;
    return (a > 0.f) ? a : 0.2f * a;
  };
  auto raw = [&](int p) -> float {
    int i = beg + p;
    int e = eid[i], s = srcc[i];
    float av = (e < E) ? ale[(size_t)e * TH + h] : 0.f;
    return al_s[s * TH + h] + ald + av;
  };

  float mloc = -1e30f;
  cnt = 0;
  for (int p = slot; p < deg; p += 4, ++cnt) {
    float a;
    if      (cnt == 0) { a0 = fin(a0, p); a = a0; }
    else if (cnt == 1) { a1 = fin(a1, p); a = a1; }
    else if (cnt == 2) { a2 = fin(a2, p); a = a2; }
    else if (cnt == 3) { a3 = fin(a3, p); a = a3; }
    else a = fin(raw(p), p);
    mloc = fmaxf(mloc, a);
  }
  mloc = fmaxf(mloc, __shfl_xor(mloc, 16));
  mloc = fmaxf(mloc, __shfl_xor(mloc, 32));

  float dloc = 0.f;
  cnt = 0;
  for (int p = slot; p < deg; p += 4, ++cnt) {
    float a = (cnt == 0) ? a0 : (cnt == 1) ? a1 : (cnt == 2) ? a2 : (cnt == 3) ? a3
              : fin(raw(p), p);
    dloc += expf(a - mloc);
  }
  dloc += __shfl_xor(dloc, 16);
  dloc += __shfl_xor(dloc, 32);
  float dinv = 1.f / (dloc + 1e-16f);

  cnt = 0;
  for (int p = slot; p < deg; p += 4, ++cnt) {
    float a = (cnt == 0) ? a0 : (cnt == 1) ? a1 : (cnt == 2) ? a2 : (cnt == 3) ? a3
              : fin(raw(p), p);
    att[(size_t)(beg + p) * TH + h] = expf(a - mloc) * dinv;
  }
}

// src-major, LDS/barrier-free: one WAVE per src node; lane keeps 16-head xp slice.
__global__ __launch_bounds__(256) void k_csc_z(const float* __restrict__ xp,
                                               const float* __restrict__ att,
                                               const int* __restrict__ srow,
                                               const int* __restrict__ smap,
                                               int N, float* __restrict__ z) {
  int tid = threadIdx.x;
  int s = blockIdx.x * 4 + (tid >> 6);
  if (s >= N) return;
  int lane = tid & 63;
  int slot = lane >> 4, c4 = (lane & 15) * 4;
  float4 xf[16];
#pragma unroll
  for (int h = 0; h < TH; ++h)
    xf[h] = *(const float4*)&xp[(size_t)s * THC + h * 64 + c4];
  int beg = srow[s], end = srow[s + 1];
  for (int j = beg + slot; j < end; j += 4) {
    int i = smap[j];
    const float* ar = &att[(size_t)i * TH];
    float4 a0 = *(const float4*)&ar[0];
    float4 a1 = *(const float4*)&ar[4];
    float4 a2 = *(const float4*)&ar[8];
    float4 a3 = *(const float4*)&ar[12];
    float aw[16] = {a0.x, a0.y, a0.z, a0.w, a1.x, a1.y, a1.z, a1.w,
                    a2.x, a2.y, a2.z, a2.w, a3.x, a3.y, a3.z, a3.w};
    float4 acc = make_float4(0.f, 0.f, 0.f, 0.f);
#pragma unroll
    for (int hh = 0; hh < TH; ++hh) {
      acc.x += aw[hh] * xf[hh].x; acc.y += aw[hh] * xf[hh].y;
      acc.z += aw[hh] * xf[hh].z; acc.w += aw[hh] * xf[hh].w;
    }
    *(float4*)&z[(size_t)i * 64 + c4] = acc;
  }
}

// per-dst: sum contiguous z segment, head-mean + bias + relu.
// Optionally ALSO writes the bf16 hi/lo split of the output (fuses layer-2's
// k_prep_x). Pad rows of obh/obl stay zero from layer-1's k_prep_x.
__global__ __launch_bounds__(256) void k_sum_z(const float* __restrict__ z,
                                               const int* __restrict__ row_start,
                                               const float* __restrict__ bias, int N,
                                               float* __restrict__ out,
                                               unsigned short* __restrict__ obh,
                                               unsigned short* __restrict__ obl) {
  int tid = threadIdx.x;
  int n = blockIdx.x * 16 + (tid >> 4);
  int c4 = (tid & 15) * 4;
  if (n >= N) return;
  int beg = row_start[n], end = row_start[n + 1];
  float4 acc = make_float4(0.f, 0.f, 0.f, 0.f);
  for (int i = beg; i < end; ++i) {
    float4 v = *(const float4*)&z[(size_t)i * 64 + c4];
    acc.x += v.x; acc.y += v.y; acc.z += v.z; acc.w += v.w;
  }
  float4 b = *(const float4*)&bias[c4];
  float o[4];
  o[0] = fmaxf(acc.x * (1.0f / TH) + b.x, 0.f);
  o[1] = fmaxf(acc.y * (1.0f / TH) + b.y, 0.f);
  o[2] = fmaxf(acc.z * (1.0f / TH) + b.z, 0.f);
  o[3] = fmaxf(acc.w * (1.0f / TH) + b.w, 0.f);
  if (out) *(float4*)&out[(size_t)n * 64 + c4] = make_float4(o[0], o[1], o[2], o[3]);
  if (obh) {
    unsigned H32[2], L32[2];
#pragma unroll
    for (int p = 0; p < 2; ++p) {
      unsigned short h0 = f2bf(o[2 * p]), h1 = f2bf(o[2 * p + 1]);
      unsigned short l0 = f2bf(o[2 * p] - bf2f(h0)), l1 = f2bf(o[2 * p + 1] - bf2f(h1));
      H32[p] = (unsigned)h0 | ((unsigned)h1 << 16);
      L32[p] = (unsigned)l0 | ((unsigned)l1 << 16);
    }
    *(uint2*)&obh[(size_t)n * TD + c4] = make_uint2(H32[0], H32[1]);
    *(uint2*)&obl[(size_t)n * TD + c4] = make_uint2(L32[0], L32[1]);
  }
}

// ---------------- launch ----------------

extern "C" void kernel_launch(void* const* d_in, const int* in_sizes, int n_in,
                              void* d_out, int out_size, void* d_ws, size_t ws_size,
                              hipStream_t stream) {
  const float* x   = (const float*)d_in[0];
  const int*   ei  = (const int*)d_in[1];
  const float* ea  = (const float*)d_in[2];
  const float* W1  = (const float*)d_in[3];
  const float* as1 = (const float*)d_in[4];
  const float* ad1 = (const float*)d_in[5];
  const float* We1 = (const float*)d_in[6];
  const float* ae1 = (const float*)d_in[7];
  const float* b1  = (const float*)d_in[8];
  const float* W2  = (const float*)d_in[9];
  const float* as2 = (const float*)d_in[10];
  const float* ad2 = (const float*)d_in[11];
  const float* We2 = (const float*)d_in[12];
  const float* ae2 = (const float*)d_in[13];
  const float* b2  = (const float*)d_in[14];

  const int N  = in_sizes[0] / TD;   // 20000
  const int E  = in_sizes[1] / 2;    // 100000
  const int EN = E + N;              // 120000 (with self-loops)
  const int* srcA = ei;
  const int* dstA = ei + E;

  char* w = (char*)d_ws;
  auto alloc = [&](size_t bytes) {
    char* p = w;
    w += (bytes + 255) & ~(size_t)255;
    return p;
  };
  int*   deg2      = (int*)alloc((size_t)2 * N * 4);      // degd | degs
  int*   degd      = deg2;
  int*   degs      = deg2 + N;
  int*   row_start = (int*)alloc((size_t)(N + 1) * 4);
  int*   srow      = (int*)alloc((size_t)(N + 1) * 4);
  int*   cursor    = (int*)alloc((size_t)N * 4);
  int*   scursor   = (int*)alloc((size_t)N * 4);
  int*   eid       = (int*)alloc((size_t)EN * 4);
  int*   srcc      = (int*)alloc((size_t)EN * 4);
  int*   inv       = (int*)alloc((size_t)EN * 4);
  int*   smap      = (int*)alloc((size_t)EN * 4);
  float* xp        = (float*)alloc((size_t)N * THC * 4);  // 82 MB
  float* al_s      = (float*)alloc((size_t)N * TH * 4);
  float* al_d      = (float*)alloc((size_t)N * TH * 4);
  float* ale1      = (float*)alloc((size_t)E * TH * 4);   // 6.4 MB
  float* ale2      = (float*)alloc((size_t)E * TH * 4);   // 6.4 MB
  float* att       = (float*)alloc((size_t)EN * TH * 4);  // 7.7 MB
  float* z         = (float*)alloc((size_t)EN * TC * 4);  // 30.7 MB
  float* w_e       = (float*)alloc((size_t)2 * TD * TH * 4);
  const int nrb  = (N + 63) / 64;    // 313 row blocks (64 rows each)
  const int Npad = nrb * 64;         // 20032
  unsigned short* xbh = (unsigned short*)alloc((size_t)Npad * TD * 2);
  unsigned short* xbl = (unsigned short*)alloc((size_t)Npad * TD * 2);
  unsigned short* Wbh = (unsigned short*)alloc((size_t)2 * 64 * 2 * 64 * 8 * 2);
  unsigned short* Wbl = (unsigned short*)alloc((size_t)2 * 64 * 2 * 64 * 8 * 2);
  unsigned short* Webh = (unsigned short*)alloc((size_t)4 * 512 * 2);
  unsigned short* Webl = (unsigned short*)alloc((size_t)4 * 512 * 2);

  // CSR (by dst) + CSC (by src) build, shared by both layers
  hipMemsetAsync(deg2, 0, (size_t)2 * N * 4, stream);
  k_count2<<<(EN + 255) / 256, 256, 0, stream>>>(srcA, dstA, E, N, degd, degs);
  k_scan2<<<2, 1024, 0, stream>>>(degd, N, row_start, cursor, degs, srow, scursor);
  k_scatter_dst<<<(EN + 255) / 256, 256, 0, stream>>>(srcA, dstA, E, N, cursor, eid, srcc, inv);
  k_scatter_src<<<(EN + 255) / 256, 256, 0, stream>>>(srcA, E, N, scursor, inv, smap);

  // W fragment-pack + edge-attention logits for BOTH layers up-front (MFMA)
  k_prep_w<<<(2 * 64 * 2 * 64 + 255) / 256, 256, 0, stream>>>(W1, W2, Wbh, Wbl);
  k_we2<<<8, 256, 0, stream>>>(We1, ae1, We2, ae2, w_e);
  k_pack_we<<<1, 256, 0, stream>>>(w_e, Webh, Webl);
  k_al_e_mfma<<<(E + 63) / 64, 256, 0, stream>>>(ea, Webh, Webl, E, ale1, ale2);

  const int mmgrid = nrb * 8;        // 2504 blocks (64 rows x 2 heads), XCD-swizzled
  const size_t WBL = 64 * 2 * 64 * 8;  // per-layer Wb elements

  // layer 1 (k_sum_z writes the bf16 split of h directly -> no layer-2 prep)
  k_prep_x<<<(Npad * 8 + 255) / 256, 256, 0, stream>>>(x, N, Npad, xbh, xbl);
  k_matmul_mfma<<<mmgrid, 256, 0, stream>>>(xbh, xbl, Wbh, Wbl, as1, ad1,
                                            N, nrb, xp, al_s, al_d);
  k_att<<<(N + 3) / 4, 256, 0, stream>>>(al_s, al_d, ale1, row_start, eid, srcc, E, N, att);
  k_csc_z<<<(N + 3) / 4, 256, 0, stream>>>(xp, att, srow, smap, N, z);
  k_sum_z<<<(N + 15) / 16, 256, 0, stream>>>(z, row_start, b1, N, nullptr, xbh, xbl);

  // layer 2
  k_matmul_mfma<<<mmgrid, 256, 0, stream>>>(xbh, xbl, Wbh + WBL, Wbl + WBL, as2, ad2,
                                            N, nrb, xp, al_s, al_d);
  k_att<<<(N + 3) / 4, 256, 0, stream>>>(al_s, al_d, ale2, row_start, eid, srcc, E, N, att);
  k_csc_z<<<(N + 3) / 4, 256, 0, stream>>>(xp, att, srow, smap, N, z);
  k_sum_z<<<(N + 15) / 16, 256, 0, stream>>>(z, row_start, b2, N, (float*)d_out, nullptr, nullptr);
}

// Round 21
// 239.028 us; speedup vs baseline: 1.1553x; 1.0046x over previous
//
#include <hip/hip_runtime.h>

// GAT (2-layer, PyG GATConv semantics) on MI355X — src-major aggregation,
// bf16-split MFMA for BOTH the feature GEMM and the edge-logit GEMM.
// This is the verbatim measured-best source (240.9 us R15 / 240.1 us R18).
// N=20000 nodes, E=100000 edges (+N self-loops), D=64, H=16 heads, C=64 ch/head.
constexpr int TD  = 64;      // input feature dim
constexpr int TH  = 16;      // heads
constexpr int TC  = 64;      // channels per head
constexpr int THC = TH * TC; // 1024

typedef short bf16x8 __attribute__((ext_vector_type(8)));
typedef unsigned short u16x8 __attribute__((ext_vector_type(8)));
typedef float f32x4 __attribute__((ext_vector_type(4)));

static __device__ __forceinline__ unsigned short f2bf(float f) {  // RNE f32->bf16
  unsigned u = __float_as_uint(f);
  u += 0x7FFF + ((u >> 16) & 1);
  return (unsigned short)(u >> 16);
}
static __device__ __forceinline__ float bf2f(unsigned short h) {
  return __uint_as_float(((unsigned)h) << 16);
}

// ---------------- CSR/CSC build (once, shared by both layers) ----------------

__global__ void k_count2(const int* __restrict__ src, const int* __restrict__ dst,
                         int E, int N, int* __restrict__ degd, int* __restrict__ degs) {
  int e = blockIdx.x * blockDim.x + threadIdx.x;
  if (e >= E + N) return;
  int s, d;
  if (e < E) { s = src[e]; d = dst[e]; } else { s = d = e - E; }
  atomicAdd(&degd[d], 1);
  atomicAdd(&degs[s], 1);
}

// hierarchical exclusive scan, 1024 threads (R13: serial version was 48 us, #1
// kernel — latency-bound at 2 blocks; this is ~4 us). block 0: dst, block 1: src.
__global__ __launch_bounds__(1024) void k_scan2(
    const int* __restrict__ degd, int N,
    int* __restrict__ row_start, int* __restrict__ cursor,
    const int* __restrict__ degs,
    int* __restrict__ srow, int* __restrict__ scursor) {
  const int* dg = blockIdx.x ? degs : degd;
  int* rs = blockIdx.x ? srow : row_start;
  int* cu = blockIdx.x ? scursor : cursor;
  __shared__ int wsum[16];
  int t = threadIdx.x;
  int chunk = (N + 1023) / 1024;
  int lo = min(t * chunk, N), hi = min(lo + chunk, N);
  int s = 0;
  for (int i = lo; i < hi; ++i) s += dg[i];
  int lane = t & 63, wid = t >> 6;
  int v = s;                              // wave inclusive scan
  for (int d = 1; d < 64; d <<= 1) {
    int u = __shfl_up(v, d, 64);
    if (lane >= d) v += u;
  }
  if (lane == 63) wsum[wid] = v;
  __syncthreads();
  if (t < 16) {                           // scan the 16 wave totals
    int wv = wsum[t];
    for (int d = 1; d < 16; d <<= 1) {
      int u = __shfl_up(wv, d, 16);
      if (t >= d) wv += u;
    }
    wsum[t] = wv;                         // inclusive
  }
  __syncthreads();
  int waveoff = wid ? wsum[wid - 1] : 0;
  int run = waveoff + (v - s);            // exclusive prefix of this thread's chunk
  for (int i = lo; i < hi; ++i) {
    rs[i] = run; cu[i] = run; run += dg[i];
  }
  if (t == 1023) rs[N] = waveoff + v;     // grand total
}

__global__ void k_scatter_dst(const int* __restrict__ src, const int* __restrict__ dst,
                              int E, int N, int* __restrict__ cursor,
                              int* __restrict__ eid, int* __restrict__ srcc,
                              int* __restrict__ inv) {
  int e = blockIdx.x * blockDim.x + threadIdx.x;
  if (e >= E + N) return;
  int s, d;
  if (e < E) { s = src[e]; d = dst[e]; } else { s = d = e - E; }
  int pos = atomicAdd(&cursor[d], 1);
  eid[pos] = e; srcc[pos] = s; inv[e] = pos;
}

__global__ void k_scatter_src(const int* __restrict__ src, int E, int N,
                              int* __restrict__ scursor, const int* __restrict__ inv,
                              int* __restrict__ smap) {
  int e = blockIdx.x * blockDim.x + threadIdx.x;
  if (e >= E + N) return;
  int s = (e < E) ? src[e] : (e - E);
  int j = atomicAdd(&scursor[s], 1);
  smap[j] = inv[e];
}

// ---------------- bf16-split prep ----------------

// Pack W (both layers) into B-fragment order for mfma_f32_16x16x32_bf16:
// B[k][j]: j = lane&15, k = ks*32 + (lane>>4)*8 + i.
// Flat: Wb[((layer*64 + ct)*2 + ks)*512 + lane*8 + i], ct = 16-col tile.
__global__ void k_prep_w(const float* __restrict__ W1, const float* __restrict__ W2,
                         unsigned short* __restrict__ Wbh, unsigned short* __restrict__ Wbl) {
  int t = blockIdx.x * 256 + threadIdx.x;   // t = ((layer*64+ct)*2+ks)*64+lane
  if (t >= 2 * 64 * 2 * 64) return;
  int lane = t & 63, ks = (t >> 6) & 1, ct = (t >> 7) & 63, layer = t >> 13;
  const float* W = layer ? W2 : W1;
  int col = ct * 16 + (lane & 15);
  int kb = ks * 32 + ((lane >> 4) << 3);
  u16x8 H, L;
#pragma unroll
  for (int i = 0; i < 8; ++i) {
    float v = W[(size_t)(kb + i) * THC + col];
    unsigned short hi = f2bf(v);
    H[i] = hi;
    L[i] = f2bf(v - bf2f(hi));
  }
  *(u16x8*)&Wbh[(size_t)t * 8] = H;
  *(u16x8*)&Wbl[(size_t)t * 8] = L;
}

// Split input rows into bf16 hi/lo, row-major [Npad][64]; pad rows zero.
// (Only needed for layer-1 input x; layer-2 split is fused into k_sum_z.)
__global__ __launch_bounds__(256) void k_prep_x(const float* __restrict__ xin, int N, int Npad,
                                                unsigned short* __restrict__ xbh,
                                                unsigned short* __restrict__ xbl) {
  int t = blockIdx.x * 256 + threadIdx.x;   // one 8-elem chunk
  if (t >= Npad * 8) return;
  int row = t >> 3, c8 = (t & 7) * 8;
  u16x8 H = {0, 0, 0, 0, 0, 0, 0, 0}, L = {0, 0, 0, 0, 0, 0, 0, 0};
  if (row < N) {
    float4 v0 = *(const float4*)&xin[(size_t)row * TD + c8];
    float4 v1 = *(const float4*)&xin[(size_t)row * TD + c8 + 4];
    float v[8] = {v0.x, v0.y, v0.z, v0.w, v1.x, v1.y, v1.z, v1.w};
#pragma unroll
    for (int i = 0; i < 8; ++i) {
      unsigned short hi = f2bf(v[i]);
      H[i] = hi;
      L[i] = f2bf(v[i] - bf2f(hi));
    }
  }
  *(u16x8*)&xbh[(size_t)row * TD + c8] = H;
  *(u16x8*)&xbl[(size_t)row * TD + c8] = L;
}

// ---------------- MFMA feature GEMM ----------------

// xp = x @ W via bf16-split (3 MFMA terms: hh + hl + lh; lo*lo ~ 2^-18, dropped).
// Block = 64 rows x 128 cols (head pair), 4 waves; wave w owns rows r0+16w..+16.
// No LDS, no barriers. Fused epilogue: al_s/al_d via 16-lane shfl reduce.
// D layout (m89-verified): col = lane&15, row = (lane>>4)*4 + reg.
__global__ __launch_bounds__(256) void k_matmul_mfma(
    const unsigned short* __restrict__ xbh, const unsigned short* __restrict__ xbl,
    const unsigned short* __restrict__ Wbh, const unsigned short* __restrict__ Wbl,
    const float* __restrict__ a_src, const float* __restrict__ a_dst,
    int N, int nrb, float* __restrict__ xp,
    float* __restrict__ al_s, float* __restrict__ al_d) {
  int tid = threadIdx.x;
  // bijective XCD swizzle (measured: keeps FETCH L2-resident, R8/R9)
  int nwg = nrb * 8;
  int wg = blockIdx.x;
  int q = nwg >> 3, rm = nwg & 7;
  int xcd = wg & 7, off = wg >> 3;
  int g = (xcd < rm ? xcd * (q + 1) : rm * (q + 1) + (xcd - rm) * q) + off;
  int hp = g & 7;                    // head pair
  int rb = g >> 3;
  int r0 = rb * 64;
  int w = tid >> 6, l = tid & 63;

  int arow = r0 + w * 16 + (l & 15);
  const unsigned short* xh = xbh + (size_t)arow * TD + ((l >> 4) << 3);
  const unsigned short* xl = xbl + (size_t)arow * TD + ((l >> 4) << 3);
  bf16x8 ah0 = *(const bf16x8*)xh;
  bf16x8 ah1 = *(const bf16x8*)(xh + 32);
  bf16x8 alo0 = *(const bf16x8*)xl;
  bf16x8 alo1 = *(const bf16x8*)(xl + 32);

  f32x4 acc[8];
  int ct0 = hp * 8;
#pragma unroll
  for (int nt = 0; nt < 8; ++nt) {
    size_t base = ((size_t)(ct0 + nt) * 2) * 512 + l * 8;
    bf16x8 bh0 = *(const bf16x8*)&Wbh[base];
    bf16x8 bh1 = *(const bf16x8*)&Wbh[base + 512];
    bf16x8 bl0 = *(const bf16x8*)&Wbl[base];
    bf16x8 bl1 = *(const bf16x8*)&Wbl[base + 512];
    f32x4 a = {0.f, 0.f, 0.f, 0.f};
    a = __builtin_amdgcn_mfma_f32_16x16x32_bf16(ah0, bh0, a, 0, 0, 0);
    a = __builtin_amdgcn_mfma_f32_16x16x32_bf16(ah1, bh1, a, 0, 0, 0);
    a = __builtin_amdgcn_mfma_f32_16x16x32_bf16(ah0, bl0, a, 0, 0, 0);
    a = __builtin_amdgcn_mfma_f32_16x16x32_bf16(ah1, bl1, a, 0, 0, 0);
    a = __builtin_amdgcn_mfma_f32_16x16x32_bf16(alo0, bh0, a, 0, 0, 0);
    a = __builtin_amdgcn_mfma_f32_16x16x32_bf16(alo1, bh1, a, 0, 0, 0);
    acc[nt] = a;
  }

  int rbase = r0 + w * 16 + ((l >> 4) << 2);
  int cl = l & 15;
#pragma unroll
  for (int nt = 0; nt < 8; ++nt) {
    int colg = hp * 128 + nt * 16 + cl;
#pragma unroll
    for (int r = 0; r < 4; ++r) {
      int rowg = rbase + r;
      if (rowg < N) xp[(size_t)rowg * THC + colg] = acc[nt][r];
    }
  }
  // fused al_s/al_d
#pragma unroll
  for (int hh = 0; hh < 2; ++hh) {
    int h = 2 * hp + hh;
    float as0 = a_src[h * TC + 0 * 16 + cl], as1 = a_src[h * TC + 1 * 16 + cl];
    float as2 = a_src[h * TC + 2 * 16 + cl], as3 = a_src[h * TC + 3 * 16 + cl];
    float ad0 = a_dst[h * TC + 0 * 16 + cl], ad1 = a_dst[h * TC + 1 * 16 + cl];
    float ad2 = a_dst[h * TC + 2 * 16 + cl], ad3 = a_dst[h * TC + 3 * 16 + cl];
#pragma unroll
    for (int r = 0; r < 4; ++r) {
      float ps = acc[hh * 4 + 0][r] * as0 + acc[hh * 4 + 1][r] * as1 +
                 acc[hh * 4 + 2][r] * as2 + acc[hh * 4 + 3][r] * as3;
      float pd = acc[hh * 4 + 0][r] * ad0 + acc[hh * 4 + 1][r] * ad1 +
                 acc[hh * 4 + 2][r] * ad2 + acc[hh * 4 + 3][r] * ad3;
      for (int m = 8; m >= 1; m >>= 1) {
        ps += __shfl_xor(ps, m, 16);
        pd += __shfl_xor(pd, m, 16);
      }
      int rowg = rbase + r;
      if (cl == 0 && rowg < N) { al_s[rowg * TH + h] = ps; al_d[rowg * TH + h] = pd; }
    }
  }
}

// ---------------- edge-logit GEMM (MFMA) ----------------

// w_e for BOTH layers: w_e[layer][d][h] = sum_c We[d, h*64+c] * a_e[h,c]
__global__ void k_we2(const float* __restrict__ We1, const float* __restrict__ ae1,
                      const float* __restrict__ We2, const float* __restrict__ ae2,
                      float* __restrict__ w_e) {
  int t = blockIdx.x * blockDim.x + threadIdx.x;
  if (t >= 2 * TD * TH) return;
  int layer = t >> 10, tt = t & 1023;
  int d = tt >> 4, h = tt & 15;
  const float* We = layer ? We2 : We1;
  const float* ae = layer ? ae2 : ae1;
  float s = 0.f;
  for (int c = 0; c < TC; ++c) s += We[(size_t)d * THC + h * TC + c] * ae[h * TC + c];
  w_e[t] = s;
}

// pack w_e into B-fragment order (bf16 hi/lo): Web[(layer*2+ks)*512 + lane*8 + i],
// col j = lane&15 = head, k = ks*32 + (lane>>4)*8 + i = d.
__global__ void k_pack_we(const float* __restrict__ w_e,
                          unsigned short* __restrict__ Webh,
                          unsigned short* __restrict__ Webl) {
  int t = threadIdx.x;               // 256 threads, 1 block
  int lane = t & 63, ks = (t >> 6) & 1, layer = t >> 7;
  int h = lane & 15;
  int kb = ks * 32 + ((lane >> 4) << 3);
  u16x8 H, L;
#pragma unroll
  for (int i = 0; i < 8; ++i) {
    float v = w_e[layer * (TD * TH) + (kb + i) * TH + h];
    unsigned short hi = f2bf(v);
    H[i] = hi;
    L[i] = f2bf(v - bf2f(hi));
  }
  *(u16x8*)&Webh[(size_t)t * 8] = H;
  *(u16x8*)&Webl[(size_t)t * 8] = L;
}

// ale[e,h] for BOTH layers in one MFMA pass: [E,64] @ [64,16] x 2 layers.
// Wave handles 16 edges; A loaded fp32 from ea, bf16-split in registers
// (same verified layout as k_matmul_mfma); 12 MFMA/wave; no LDS/barriers.
// R14: LDS version was 44.8 us with 6.4M bank conflicts; this is BW-bound ~7 us.
__global__ __launch_bounds__(256) void k_al_e_mfma(
    const float* __restrict__ ea,
    const unsigned short* __restrict__ Webh, const unsigned short* __restrict__ Webl,
    int E, float* __restrict__ ale1, float* __restrict__ ale2) {
  int tid = threadIdx.x;
  int w = tid >> 6, l = tid & 63;
  int e0 = blockIdx.x * 64 + w * 16;
  int arow = e0 + (l & 15);
  int koff = (l >> 4) << 3;
  float a0[8], a1[8];
  if (arow < E) {
    float4 v0 = *(const float4*)&ea[(size_t)arow * TD + koff];
    float4 v1 = *(const float4*)&ea[(size_t)arow * TD + koff + 4];
    float4 v2 = *(const float4*)&ea[(size_t)arow * TD + 32 + koff];
    float4 v3 = *(const float4*)&ea[(size_t)arow * TD + 32 + koff + 4];
    a0[0] = v0.x; a0[1] = v0.y; a0[2] = v0.z; a0[3] = v0.w;
    a0[4] = v1.x; a0[5] = v1.y; a0[6] = v1.z; a0[7] = v1.w;
    a1[0] = v2.x; a1[1] = v2.y; a1[2] = v2.z; a1[3] = v2.w;
    a1[4] = v3.x; a1[5] = v3.y; a1[6] = v3.z; a1[7] = v3.w;
  } else {
#pragma unroll
    for (int i = 0; i < 8; ++i) { a0[i] = 0.f; a1[i] = 0.f; }
  }
  bf16x8 ah0, alo0, ah1, alo1;
#pragma unroll
  for (int i = 0; i < 8; ++i) {
    unsigned short h0 = f2bf(a0[i]);
    ah0[i] = (short)h0; alo0[i] = (short)f2bf(a0[i] - bf2f(h0));
    unsigned short h1 = f2bf(a1[i]);
    ah1[i] = (short)h1; alo1[i] = (short)f2bf(a1[i] - bf2f(h1));
  }

  f32x4 acc0 = {0.f, 0.f, 0.f, 0.f}, acc1 = {0.f, 0.f, 0.f, 0.f};
#pragma unroll
  for (int ks = 0; ks < 2; ++ks) {
    bf16x8 ah = ks ? ah1 : ah0;
    bf16x8 alo = ks ? alo1 : alo0;
    size_t b0 = (size_t)ks * 512 + l * 8;          // layer 0
    size_t b1 = (size_t)(2 + ks) * 512 + l * 8;    // layer 1
    bf16x8 bh_0 = *(const bf16x8*)&Webh[b0];
    bf16x8 bl_0 = *(const bf16x8*)&Webl[b0];
    bf16x8 bh_1 = *(const bf16x8*)&Webh[b1];
    bf16x8 bl_1 = *(const bf16x8*)&Webl[b1];
    acc0 = __builtin_amdgcn_mfma_f32_16x16x32_bf16(ah, bh_0, acc0, 0, 0, 0);
    acc0 = __builtin_amdgcn_mfma_f32_16x16x32_bf16(ah, bl_0, acc0, 0, 0, 0);
    acc0 = __builtin_amdgcn_mfma_f32_16x16x32_bf16(alo, bh_0, acc0, 0, 0, 0);
    acc1 = __builtin_amdgcn_mfma_f32_16x16x32_bf16(ah, bh_1, acc1, 0, 0, 0);
    acc1 = __builtin_amdgcn_mfma_f32_16x16x32_bf16(ah, bl_1, acc1, 0, 0, 0);
    acc1 = __builtin_amdgcn_mfma_f32_16x16x32_bf16(alo, bh_1, acc1, 0, 0, 0);
  }

  int rbase = e0 + ((l >> 4) << 2);
  int h = l & 15;
#pragma unroll
  for (int r = 0; r < 4; ++r) {
    int e = rbase + r;
    if (e < E) {
      ale1[(size_t)e * TH + h] = acc0[r];
      ale2[(size_t)e * TH + h] = acc1[r];
    }
  }
}

// ---------------- attention / aggregation (measured-good) -------

// one WAVE per dst node, barrier/LDS-free (measured win R9): lane = h + 16*slot.
__global__ __launch_bounds__(256) void k_att(
    const float* __restrict__ al_s, const float* __restrict__ al_d,
    const float* __restrict__ ale, const int* __restrict__ row_start,
    const int* __restrict__ eid, const int* __restrict__ srcc,
    int E, int N, float* __restrict__ att) {
  int tid = threadIdx.x;
  int n = blockIdx.x * 4 + (tid >> 6);
  if (n >= N) return;
  int lane = tid & 63;
  int h = lane & 15, slot = lane >> 4;
  int beg = row_start[n], end = row_start[n + 1], deg = end - beg;
  float ald = al_d[n * TH + h];

  float a0 = 0.f, a1 = 0.f, a2 = 0.f, a3 = 0.f;
  float asum = 0.f;
  int selfp = -1;
  int cnt = 0;
  for (int p = slot; p < deg; p += 4, ++cnt) {
    int i = beg + p;
    int e = eid[i], s = srcc[i];
    float av = 0.f;
    if (e < E) { av = ale[(size_t)e * TH + h]; asum += av; }
    else selfp = p;
    float a = al_s[s * TH + h] + ald + av;
    if (cnt == 0) a0 = a; else if (cnt == 1) a1 = a;
    else if (cnt == 2) a2 = a; else if (cnt == 3) a3 = a;
  }
  asum += __shfl_xor(asum, 16);
  asum += __shfl_xor(asum, 32);
  float lale = asum / (float)max(deg - 1, 1);

  auto fin = [&](float a, int p) -> float {
    if (p == selfp) a += lale;
    return (a > 0.f) ? a : 0.2f * a;
  };
  auto raw = [&](int p) -> float {
    int i = beg + p;
    int e = eid[i], s = srcc[i];
    float av = (e < E) ? ale[(size_t)e * TH + h] : 0.f;
    return al_s[s * TH + h] + ald + av;
  };

  float mloc = -1e30f;
  cnt = 0;
  for (int p = slot; p < deg; p += 4, ++cnt) {
    float a;
    if      (cnt == 0) { a0 = fin(a0, p); a = a0; }
    else if (cnt == 1) { a1 = fin(a1, p); a = a1; }
    else if (cnt == 2) { a2 = fin(a2, p); a = a2; }
    else if (cnt == 3) { a3 = fin(a3, p); a = a3; }
    else a = fin(raw(p), p);
    mloc = fmaxf(mloc, a);
  }
  mloc = fmaxf(mloc, __shfl_xor(mloc, 16));
  mloc = fmaxf(mloc, __shfl_xor(mloc, 32));

  float dloc = 0.f;
  cnt = 0;
  for (int p = slot; p < deg; p += 4, ++cnt) {
    float a = (cnt == 0) ? a0 : (cnt == 1) ? a1 : (cnt == 2) ? a2 : (cnt == 3) ? a3
              : fin(raw(p), p);
    dloc += expf(a - mloc);
  }
  dloc += __shfl_xor(dloc, 16);
  dloc += __shfl_xor(dloc, 32);
  float dinv = 1.f / (dloc + 1e-16f);

  cnt = 0;
  for (int p = slot; p < deg; p += 4, ++cnt) {
    float a = (cnt == 0) ? a0 : (cnt == 1) ? a1 : (cnt == 2) ? a2 : (cnt == 3) ? a3
              : fin(raw(p), p);
    att[(size_t)(beg + p) * TH + h] = expf(a - mloc) * dinv;
  }
}

// src-major, LDS/barrier-free: one WAVE per src node; lane keeps 16-head xp slice.
__global__ __launch_bounds__(256) void k_csc_z(const float* __restrict__ xp,
                                               const float* __restrict__ att,
                                               const int* __restrict__ srow,
                                               const int* __restrict__ smap,
                                               int N, float* __restrict__ z) {
  int tid = threadIdx.x;
  int s = blockIdx.x * 4 + (tid >> 6);
  if (s >= N) return;
  int lane = tid & 63;
  int slot = lane >> 4, c4 = (lane & 15) * 4;
  float4 xf[16];
#pragma unroll
  for (int h = 0; h < TH; ++h)
    xf[h] = *(const float4*)&xp[(size_t)s * THC + h * 64 + c4];
  int beg = srow[s], end = srow[s + 1];
  for (int j = beg + slot; j < end; j += 4) {
    int i = smap[j];
    const float* ar = &att[(size_t)i * TH];
    float4 a0 = *(const float4*)&ar[0];
    float4 a1 = *(const float4*)&ar[4];
    float4 a2 = *(const float4*)&ar[8];
    float4 a3 = *(const float4*)&ar[12];
    float aw[16] = {a0.x, a0.y, a0.z, a0.w, a1.x, a1.y, a1.z, a1.w,
                    a2.x, a2.y, a2.z, a2.w, a3.x, a3.y, a3.z, a3.w};
    float4 acc = make_float4(0.f, 0.f, 0.f, 0.f);
#pragma unroll
    for (int hh = 0; hh < TH; ++hh) {
      acc.x += aw[hh] * xf[hh].x; acc.y += aw[hh] * xf[hh].y;
      acc.z += aw[hh] * xf[hh].z; acc.w += aw[hh] * xf[hh].w;
    }
    *(float4*)&z[(size_t)i * 64 + c4] = acc;
  }
}

// per-dst: sum contiguous z segment, head-mean + bias + relu.
// Optionally ALSO writes the bf16 hi/lo split of the output (fuses layer-2's
// k_prep_x). Pad rows of obh/obl stay zero from layer-1's k_prep_x.
__global__ __launch_bounds__(256) void k_sum_z(const float* __restrict__ z,
                                               const int* __restrict__ row_start,
                                               const float* __restrict__ bias, int N,
                                               float* __restrict__ out,
                                               unsigned short* __restrict__ obh,
                                               unsigned short* __restrict__ obl) {
  int tid = threadIdx.x;
  int n = blockIdx.x * 16 + (tid >> 4);
  int c4 = (tid & 15) * 4;
  if (n >= N) return;
  int beg = row_start[n], end = row_start[n + 1];
  float4 acc = make_float4(0.f, 0.f, 0.f, 0.f);
  for (int i = beg; i < end; ++i) {
    float4 v = *(const float4*)&z[(size_t)i * 64 + c4];
    acc.x += v.x; acc.y += v.y; acc.z += v.z; acc.w += v.w;
  }
  float4 b = *(const float4*)&bias[c4];
  float o[4];
  o[0] = fmaxf(acc.x * (1.0f / TH) + b.x, 0.f);
  o[1] = fmaxf(acc.y * (1.0f / TH) + b.y, 0.f);
  o[2] = fmaxf(acc.z * (1.0f / TH) + b.z, 0.f);
  o[3] = fmaxf(acc.w * (1.0f / TH) + b.w, 0.f);
  if (out) *(float4*)&out[(size_t)n * 64 + c4] = make_float4(o[0], o[1], o[2], o[3]);
  if (obh) {
    unsigned H32[2], L32[2];
#pragma unroll
    for (int p = 0; p < 2; ++p) {
      unsigned short h0 = f2bf(o[2 * p]), h1 = f2bf(o[2 * p + 1]);
      unsigned short l0 = f2bf(o[2 * p] - bf2f(h0)), l1 = f2bf(o[2 * p + 1] - bf2f(h1));
      H32[p] = (unsigned)h0 | ((unsigned)h1 << 16);
      L32[p] = (unsigned)l0 | ((unsigned)l1 << 16);
    }
    *(uint2*)&obh[(size_t)n * TD + c4] = make_uint2(H32[0], H32[1]);
    *(uint2*)&obl[(size_t)n * TD + c4] = make_uint2(L32[0], L32[1]);
  }
}

// ---------------- launch ----------------

extern "C" void kernel_launch(void* const* d_in, const int* in_sizes, int n_in,
                              void* d_out, int out_size, void* d_ws, size_t ws_size,
                              hipStream_t stream) {
  const float* x   = (const float*)d_in[0];
  const int*   ei  = (const int*)d_in[1];
  const float* ea  = (const float*)d_in[2];
  const float* W1  = (const float*)d_in[3];
  const float* as1 = (const float*)d_in[4];
  const float* ad1 = (const float*)d_in[5];
  const float* We1 = (const float*)d_in[6];
  const float* ae1 = (const float*)d_in[7];
  const float* b1  = (const float*)d_in[8];
  const float* W2  = (const float*)d_in[9];
  const float* as2 = (const float*)d_in[10];
  const float* ad2 = (const float*)d_in[11];
  const float* We2 = (const float*)d_in[12];
  const float* ae2 = (const float*)d_in[13];
  const float* b2  = (const float*)d_in[14];

  const int N  = in_sizes[0] / TD;   // 20000
  const int E  = in_sizes[1] / 2;    // 100000
  const int EN = E + N;              // 120000 (with self-loops)
  const int* srcA = ei;
  const int* dstA = ei + E;

  char* w = (char*)d_ws;
  auto alloc = [&](size_t bytes) {
    char* p = w;
    w += (bytes + 255) & ~(size_t)255;
    return p;
  };
  int*   deg2      = (int*)alloc((size_t)2 * N * 4);      // degd | degs
  int*   degd      = deg2;
  int*   degs      = deg2 + N;
  int*   row_start = (int*)alloc((size_t)(N + 1) * 4);
  int*   srow      = (int*)alloc((size_t)(N + 1) * 4);
  int*   cursor    = (int*)alloc((size_t)N * 4);
  int*   scursor   = (int*)alloc((size_t)N * 4);
  int*   eid       = (int*)alloc((size_t)EN * 4);
  int*   srcc      = (int*)alloc((size_t)EN * 4);
  int*   inv       = (int*)alloc((size_t)EN * 4);
  int*   smap      = (int*)alloc((size_t)EN * 4);
  float* xp        = (float*)alloc((size_t)N * THC * 4);  // 82 MB
  float* al_s      = (float*)alloc((size_t)N * TH * 4);
  float* al_d      = (float*)alloc((size_t)N * TH * 4);
  float* ale1      = (float*)alloc((size_t)E * TH * 4);   // 6.4 MB
  float* ale2      = (float*)alloc((size_t)E * TH * 4);   // 6.4 MB
  float* att       = (float*)alloc((size_t)EN * TH * 4);  // 7.7 MB
  float* z         = (float*)alloc((size_t)EN * TC * 4);  // 30.7 MB
  float* w_e       = (float*)alloc((size_t)2 * TD * TH * 4);
  const int nrb  = (N + 63) / 64;    // 313 row blocks (64 rows each)
  const int Npad = nrb * 64;         // 20032
  unsigned short* xbh = (unsigned short*)alloc((size_t)Npad * TD * 2);
  unsigned short* xbl = (unsigned short*)alloc((size_t)Npad * TD * 2);
  unsigned short* Wbh = (unsigned short*)alloc((size_t)2 * 64 * 2 * 64 * 8 * 2);
  unsigned short* Wbl = (unsigned short*)alloc((size_t)2 * 64 * 2 * 64 * 8 * 2);
  unsigned short* Webh = (unsigned short*)alloc((size_t)4 * 512 * 2);
  unsigned short* Webl = (unsigned short*)alloc((size_t)4 * 512 * 2);

  // CSR (by dst) + CSC (by src) build, shared by both layers
  hipMemsetAsync(deg2, 0, (size_t)2 * N * 4, stream);
  k_count2<<<(EN + 255) / 256, 256, 0, stream>>>(srcA, dstA, E, N, degd, degs);
  k_scan2<<<2, 1024, 0, stream>>>(degd, N, row_start, cursor, degs, srow, scursor);
  k_scatter_dst<<<(EN + 255) / 256, 256, 0, stream>>>(srcA, dstA, E, N, cursor, eid, srcc, inv);
  k_scatter_src<<<(EN + 255) / 256, 256, 0, stream>>>(srcA, E, N, scursor, inv, smap);

  // W fragment-pack + edge-attention logits for BOTH layers up-front (MFMA)
  k_prep_w<<<(2 * 64 * 2 * 64 + 255) / 256, 256, 0, stream>>>(W1, W2, Wbh, Wbl);
  k_we2<<<8, 256, 0, stream>>>(We1, ae1, We2, ae2, w_e);
  k_pack_we<<<1, 256, 0, stream>>>(w_e, Webh, Webl);
  k_al_e_mfma<<<(E + 63) / 64, 256, 0, stream>>>(ea, Webh, Webl, E, ale1, ale2);

  const int mmgrid = nrb * 8;        // 2504 blocks (64 rows x 2 heads), XCD-swizzled
  const size_t WBL = 64 * 2 * 64 * 8;  // per-layer Wb elements

  // layer 1 (k_sum_z writes the bf16 split of h directly -> no layer-2 prep)
  k_prep_x<<<(Npad * 8 + 255) / 256, 256, 0, stream>>>(x, N, Npad, xbh, xbl);
  k_matmul_mfma<<<mmgrid, 256, 0, stream>>>(xbh, xbl, Wbh, Wbl, as1, ad1,
                                            N, nrb, xp, al_s, al_d);
  k_att<<<(N + 3) / 4, 256, 0, stream>>>(al_s, al_d, ale1, row_start, eid, srcc, E, N, att);
  k_csc_z<<<(N + 3) / 4, 256, 0, stream>>>(xp, att, srow, smap, N, z);
  k_sum_z<<<(N + 15) / 16, 256, 0, stream>>>(z, row_start, b1, N, nullptr, xbh, xbl);

  // layer 2
  k_matmul_mfma<<<mmgrid, 256, 0, stream>>>(xbh, xbl, Wbh + WBL, Wbl + WBL, as2, ad2,
                                            N, nrb, xp, al_s, al_d);
  k_att<<<(N + 3) / 4, 256, 0, stream>>>(al_s, al_d, ale2, row_start, eid, srcc, E, N, att);
  k_csc_z<<<(N + 3) / 4, 256, 0, stream>>>(xp, att, srow, smap, N, z);
  k_sum_z<<<(N + 15) / 16, 256, 0, stream>>>(z, row_start, b2, N, (float*)d_out, nullptr, nullptr);
}